// Round 1
// baseline (2857.295 us; speedup 1.0000x reference)
//
#include <hip/hip_runtime.h>

typedef __attribute__((ext_vector_type(8))) short short8;
typedef __attribute__((ext_vector_type(4))) float f32x4;

#define NEGV -10000.0f

__device__ __forceinline__ float bfu2f(unsigned short u) {
  unsigned int x = ((unsigned int)u) << 16;
  return __builtin_bit_cast(float, x);
}
__device__ __forceinline__ unsigned short f2bfu(float f) {
  unsigned int x = __builtin_bit_cast(unsigned int, f);
  x += 0x7fffu + ((x >> 16) & 1u);
  return (unsigned short)(x >> 16);
}
__device__ __forceinline__ float fsig(float x) {
  return 1.0f / (1.0f + __expf(-x));
}
__device__ __forceinline__ float ftanh(float x) {
  x = fminf(15.0f, fmaxf(-15.0f, x));
  float e = __expf(-2.0f * x);
  return (1.0f - e) / (1.0f + e);
}

// ---------------- prep: convert weights to bf16, build combined bias ----------------
__global__ __launch_bounds__(256) void prep_kernel(
    const float* __restrict__ wihf, const float* __restrict__ wihb,
    const float* __restrict__ whhf, const float* __restrict__ whhb,
    const float* __restrict__ wo, const float* __restrict__ bfv,
    const float* __restrict__ bbv,
    unsigned short* __restrict__ wih_c, unsigned short* __restrict__ whh_c,
    unsigned short* __restrict__ wout_c, float* __restrict__ bias_c) {
  size_t i = (size_t)blockIdx.x * 256 + threadIdx.x;
  const size_t n_half = 2048u * 512u;        // one direction's w_ih
  const size_t n_wih = 2u * n_half;          // 2097152*... total 4096x512
  const size_t n_wo = 24u * 1024u;
  if (i < n_wih) {
    float v = (i < n_half) ? wihf[i] : wihb[i - n_half];
    wih_c[i] = f2bfu(v);
  } else if (i < 2u * n_wih) {
    size_t j = i - n_wih;
    float v = (j < n_half) ? whhf[j] : whhb[j - n_half];
    whh_c[j] = f2bfu(v);
  } else if (i < 2u * n_wih + n_wo) {
    size_t j = i - 2u * n_wih;
    wout_c[j] = f2bfu(wo[j]);
  } else if (i < 2u * n_wih + n_wo + 4096u) {
    size_t j = i - 2u * n_wih - n_wo;
    bias_c[j] = (j < 2048u) ? bfv[j] : bbv[j - 2048u];
  }
}

// ---------------- gather: x_bf16[tb][e] = bf16(emb[xw[tb]][e]) ----------------
__global__ __launch_bounds__(64) void gather_kernel(
    const int* __restrict__ xw, const float* __restrict__ emb,
    unsigned short* __restrict__ xbf) {
  int tb = blockIdx.x;
  int l = threadIdx.x;
  int tok = xw[tb];
  const float* src = emb + (size_t)tok * 512 + l * 8;
  short8 o;
#pragma unroll
  for (int j = 0; j < 8; ++j) o[j] = (short)f2bfu(src[j]);
  *(short8*)(xbf + (size_t)tb * 512 + l * 8) = o;
}

// ---------------- GEMM: xg[16384][4096] = xbf[16384][512] @ wih_c[4096][512]^T + bias ----
__global__ __launch_bounds__(256) void gemm_xg_kernel(
    const unsigned short* __restrict__ A,   // [16384][512]
    const unsigned short* __restrict__ Bm,  // [4096][512]
    const float* __restrict__ bias,         // [4096]
    unsigned short* __restrict__ C) {       // [16384][4096] bf16
  __shared__ alignas(16) char As[16384];
  __shared__ alignas(16) char Bs[16384];
  int m0 = blockIdx.x * 128, n0 = blockIdx.y * 128;
  int tid = threadIdx.x;
  int wv = tid >> 6, l = tid & 63;
  int wm = wv >> 1, wn = wv & 1;
  int col = l & 15, quad = l >> 4;
  f32x4 zero4 = {0.f, 0.f, 0.f, 0.f};
  f32x4 acc[4][4];
#pragma unroll
  for (int i = 0; i < 4; ++i)
#pragma unroll
    for (int j = 0; j < 4; ++j) acc[i][j] = zero4;
  for (int kt = 0; kt < 8; ++kt) {
#pragma unroll
    for (int q = 0; q < 4; ++q) {
      int o = q * 4096 + tid * 16;
      int row = o >> 7;
      int cb = o & 127;
      int swz = cb ^ ((row & 7) << 4);
      short8 va = *(const short8*)(A + (size_t)(m0 + row) * 512 + kt * 64 + (cb >> 1));
      *(short8*)(As + row * 128 + swz) = va;
      short8 vb = *(const short8*)(Bm + (size_t)(n0 + row) * 512 + kt * 64 + (cb >> 1));
      *(short8*)(Bs + row * 128 + swz) = vb;
    }
    __syncthreads();
#pragma unroll
    for (int kk = 0; kk < 2; ++kk) {
      short8 af[4], bf8[4];
#pragma unroll
      for (int mi = 0; mi < 4; ++mi) {
        int r = wm * 64 + mi * 16 + col;
        int cb = kk * 64 + quad * 16;
        af[mi] = *(const short8*)(As + r * 128 + (cb ^ ((r & 7) << 4)));
      }
#pragma unroll
      for (int ni = 0; ni < 4; ++ni) {
        int r = wn * 64 + ni * 16 + col;
        int cb = kk * 64 + quad * 16;
        bf8[ni] = *(const short8*)(Bs + r * 128 + (cb ^ ((r & 7) << 4)));
      }
#pragma unroll
      for (int mi = 0; mi < 4; ++mi)
#pragma unroll
        for (int ni = 0; ni < 4; ++ni)
          acc[mi][ni] = __builtin_amdgcn_mfma_f32_16x16x32_bf16(af[mi], bf8[ni], acc[mi][ni], 0, 0, 0);
    }
    __syncthreads();
  }
#pragma unroll
  for (int ni = 0; ni < 4; ++ni) {
    int cg = n0 + wn * 64 + ni * 16 + col;
    float bv = bias[cg];
#pragma unroll
    for (int mi = 0; mi < 4; ++mi) {
#pragma unroll
      for (int r = 0; r < 4; ++r) {
        int rg = m0 + wm * 64 + mi * 16 + quad * 4 + r;
        C[(size_t)rg * 4096 + cg] = f2bfu(acc[mi][ni][r] + bv);
      }
    }
  }
}

// ---------------- persistent LSTM scan, both directions ----------------
// grid = 128 wgs: dir = wg&1, g = wg>>1 (64 wgs per direction, 8 h-units each).
// h planes layout: [t][g(64)][b(64)][8 units] bf16 -> 64KB per plane, each wg
// owns a contiguous 1KB slice (no cross-XCD false sharing), and MFMA A-frag
// ds_reads are contiguous 16B (conflict-free).
__global__ __launch_bounds__(256, 1) void scan_kernel(
    const unsigned short* __restrict__ whh,  // [2][2048][512] bf16
    const unsigned short* __restrict__ xg,   // [16384][4096] bf16
    unsigned short* __restrict__ hfp,
    unsigned short* __restrict__ hbp,
    unsigned int* __restrict__ flags) {
  int wg = blockIdx.x;
  int dir = wg & 1, g = wg >> 1;
  int u0 = g * 8;
  int tid = threadIdx.x, wv = tid >> 6, l = tid & 63;
  int col = l & 15, quad = l >> 4;
  // preload w_hh slice fragments into registers (32 gatecols x 512 K)
  short8 bfr[2][16];
#pragma unroll
  for (int n = 0; n < 2; ++n) {
    int blk = n * 2 + (col >> 3);             // 0..3 = i,f,g,o
    int gr = blk * 512 + u0 + (col & 7);
    const unsigned short* base = whh + ((size_t)dir * 2048 + gr) * 512 + quad * 8;
#pragma unroll
    for (int kk = 0; kk < 16; ++kk) bfr[n][kk] = *(const short8*)(base + kk * 32);
  }
  unsigned short* hseq = dir ? hbp : hfp;
  unsigned int* myf = flags + dir * 256;
  float cst[4] = {0.f, 0.f, 0.f, 0.f};
  __shared__ alignas(16) char hbuf[65536];
  f32x4 zero4 = {0.f, 0.f, 0.f, 0.f};
  for (int s = 0; s < 256; ++s) {
    int t = dir ? (255 - s) : s;
    // xg loads (independent of the barrier -> issue early)
    float xgv[2][4];
#pragma unroll
    for (int n = 0; n < 2; ++n) {
      int gc = dir * 2048 + (n * 2 + (col >> 3)) * 512 + u0 + (col & 7);
#pragma unroll
      for (int r = 0; r < 4; ++r) {
        int b = wv * 16 + quad * 4 + r;
        xgv[n][r] = bfu2f(xg[((size_t)t * 64 + b) * 4096 + gc]);
      }
    }
    f32x4 acc0 = zero4, acc1 = zero4;
    if (s > 0) {
      int tprev = dir ? (t + 1) : (t - 1);
      if (tid == 0) {
        while (__hip_atomic_load(myf + (s - 1), __ATOMIC_RELAXED, __HIP_MEMORY_SCOPE_AGENT) < 64u)
          __builtin_amdgcn_s_sleep(2);
        __threadfence();  // acquire: invalidate stale L1/L2 before reading peers' h
      }
      __syncthreads();
      const char* src = (const char*)hseq + (size_t)tprev * 65536;
#pragma unroll
      for (int q = 0; q < 16; ++q) {
        int o = q * 4096 + tid * 16;
        *(short8*)(hbuf + o) = *(const short8*)(src + o);
      }
      __syncthreads();
#pragma unroll
      for (int kk = 0; kk < 16; ++kk) {
        short8 a = *(const short8*)(hbuf + (kk * 4 + quad) * 1024 + (wv * 16 + col) * 16);
        acc0 = __builtin_amdgcn_mfma_f32_16x16x32_bf16(a, bfr[0][kk], acc0, 0, 0, 0);
        acc1 = __builtin_amdgcn_mfma_f32_16x16x32_bf16(a, bfr[1][kk], acc1, 0, 0, 0);
      }
    }
    char* dst = (char*)hseq + (size_t)t * 65536 + g * 1024;
    bool low = (col < 8);
#pragma unroll
    for (int r = 0; r < 4; ++r) {
      float g0 = acc0[r] + xgv[0][r];
      float g1 = acc1[r] + xgv[1][r];
      float p0 = __shfl_xor(g0, 8);
      float p1 = __shfl_xor(g1, 8);
      float iv = low ? g0 : p0;
      float fv = low ? p0 : g0;
      float gv = low ? g1 : p1;
      float ov = low ? p1 : g1;
      float cn = fsig(fv) * cst[r] + fsig(iv) * ftanh(gv);
      cst[r] = cn;
      float hv = fsig(ov) * ftanh(cn);
      if (low) {
        int b = wv * 16 + quad * 4 + r;
        *(unsigned short*)(dst + b * 16 + (col & 7) * 2) = f2bfu(hv);
      }
    }
    __syncthreads();  // drains vmcnt (stores complete) before publishing
    if (tid == 0) {
      __threadfence();  // release: flush L2 so other XCDs see our h slice
      atomicAdd(myf + s, 1u);
    }
  }
}

// ---------------- logits[t][b][k] = (hf|hb).w_out[k] + b_out, masked ----------------
__global__ __launch_bounds__(256) void logits_kernel(
    const unsigned short* __restrict__ hfp, const unsigned short* __restrict__ hbp,
    const unsigned short* __restrict__ wout, const float* __restrict__ bout,
    const int* __restrict__ y0, float* __restrict__ lg) {
  int t = blockIdx.x, tid = threadIdx.x;
  int b = tid >> 2, ks = tid & 3;
  int ytag = y0[(t + 1) * 64 + b];
  float mk = (ytag > 0) ? 1.f : 0.f;
  float av[6] = {0.f, 0.f, 0.f, 0.f, 0.f, 0.f};
  const char* pf = (const char*)hfp + (size_t)t * 65536;
  const char* pb = (const char*)hbp + (size_t)t * 65536;
  for (int uc = 0; uc < 64; ++uc) {
    short8 hv = *(const short8*)(pf + uc * 1024 + b * 16);
#pragma unroll
    for (int kk = 0; kk < 6; ++kk) {
      int k = ks * 6 + kk;
      short8 wv = *(const short8*)(wout + (size_t)k * 1024 + uc * 8);
#pragma unroll
      for (int j = 0; j < 8; ++j)
        av[kk] += bfu2f((unsigned short)hv[j]) * bfu2f((unsigned short)wv[j]);
    }
  }
  for (int uc = 0; uc < 64; ++uc) {
    short8 hv = *(const short8*)(pb + uc * 1024 + b * 16);
#pragma unroll
    for (int kk = 0; kk < 6; ++kk) {
      int k = ks * 6 + kk;
      short8 wv = *(const short8*)(wout + (size_t)k * 1024 + 512 + uc * 8);
#pragma unroll
      for (int j = 0; j < 8; ++j)
        av[kk] += bfu2f((unsigned short)hv[j]) * bfu2f((unsigned short)wv[j]);
    }
  }
#pragma unroll
  for (int kk = 0; kk < 6; ++kk) {
    int k = ks * 6 + kk;
    lg[((size_t)t * 64 + b) * 32 + k] = mk * (av[kk] + bout[k]);
  }
}

// ---------------- CRF forward + gold, one wave per batch ----------------
__global__ __launch_bounds__(64) void crf_kernel(
    const float* __restrict__ lg, const int* __restrict__ y0,
    const float* __restrict__ trans, float* __restrict__ res) {
  int b = blockIdx.x, l = threadIdx.x;
  __shared__ float tl[600];  // trans padded [24][25]
  __shared__ float sc[24];
  for (int i = l; i < 576; i += 64) tl[(i / 24) * 25 + (i % 24)] = trans[i];
  if (l < 24) sc[l] = (l == 1) ? 0.f : NEGV;
  __syncthreads();
  float gold = 0.f;
  int lens = 0;
  for (int t = l; t < 256; t += 64) {
    int y1 = y0[(t + 1) * 64 + b];
    int yp = y0[t * 64 + b];
    if (y1 > 0) {
      gold += lg[((size_t)t * 64 + b) * 32 + y1] + tl[y1 * 25 + yp];
      lens += 1;
    }
  }
#pragma unroll
  for (int off = 32; off > 0; off >>= 1) {
    gold += __shfl_down(gold, off);
    lens += __shfl_down(lens, off);
  }
  gold = __shfl(gold, 0);
  lens = __shfl(lens, 0);
  int last = y0[lens * 64 + b];
  gold += tl[2 * 25 + last];
  int lc = (l < 24) ? l : 23;
  float trow[24];
#pragma unroll
  for (int j = 0; j < 24; ++j) trow[j] = tl[lc * 25 + j];
  for (int t = 0; t < 256; ++t) {
    int y1 = y0[(t + 1) * 64 + b];
    if (y1 > 0) {
      float ns = 0.f;
      if (l < 24) {
        float ht = lg[((size_t)t * 64 + b) * 32 + l];
        float mx = -3.0e38f;
        float sj[24];
#pragma unroll
        for (int j = 0; j < 24; ++j) {
          sj[j] = sc[j] + trow[j];
          mx = fmaxf(mx, sj[j]);
        }
        float sm = 0.f;
#pragma unroll
        for (int j = 0; j < 24; ++j) sm += __expf(sj[j] - mx);
        ns = ht + mx + __logf(sm);
      }
      __syncthreads();
      if (l < 24) sc[l] = ns;
      __syncthreads();
    }
  }
  float v = (l < 24) ? sc[l] + tl[2 * 25 + l] : -3.0e38f;
  float mx = v;
#pragma unroll
  for (int off = 32; off > 0; off >>= 1) mx = fmaxf(mx, __shfl_xor(mx, off));
  float se = (l < 24) ? __expf(v - mx) : 0.f;
#pragma unroll
  for (int off = 32; off > 0; off >>= 1) se += __shfl_xor(se, off);
  float Z = mx + __logf(se);
  if (l == 0) res[b] = Z - gold;
}

__global__ __launch_bounds__(64) void reduce_kernel(const float* __restrict__ res,
                                                    float* __restrict__ out) {
  int l = threadIdx.x;
  float v = res[l];
#pragma unroll
  for (int off = 32; off > 0; off >>= 1) v += __shfl_down(v, off);
  if (l == 0) out[0] = v * (1.0f / 64.0f);
}

extern "C" void kernel_launch(void* const* d_in, const int* in_sizes, int n_in,
                              void* d_out, int out_size, void* d_ws, size_t ws_size,
                              hipStream_t stream) {
  (void)in_sizes; (void)n_in; (void)out_size; (void)ws_size;
  const int* xw = (const int*)d_in[0];
  const int* y0 = (const int*)d_in[1];
  const float* emb = (const float*)d_in[2];
  const float* wihf = (const float*)d_in[3];
  const float* whhf = (const float*)d_in[4];
  const float* bfv = (const float*)d_in[5];
  const float* wihb = (const float*)d_in[6];
  const float* whhb = (const float*)d_in[7];
  const float* bbv = (const float*)d_in[8];
  const float* wo = (const float*)d_in[9];
  const float* bo = (const float*)d_in[10];
  const float* tr = (const float*)d_in[11];
  char* ws = (char*)d_ws;
  unsigned short* xg = (unsigned short*)(ws + 0);              // 134217728 B
  unsigned short* xbf = (unsigned short*)(ws + 134217728);     // 16777216 B
  unsigned short* wih_c = (unsigned short*)(ws + 150994944);   // 4194304 B
  unsigned short* whh_c = (unsigned short*)(ws + 155189248);   // 4194304 B
  unsigned short* wout_c = (unsigned short*)(ws + 159383552);  // 49152 B
  float* bias_c = (float*)(ws + 159432704);                    // 16384 B
  unsigned short* hfp = (unsigned short*)(ws + 159449088);     // 16777216 B
  unsigned short* hbp = (unsigned short*)(ws + 176226304);     // 16777216 B
  float* lg = (float*)(ws + 193003520);                        // 2097152 B
  unsigned int* flags = (unsigned int*)(ws + 195100672);       // 4096 B
  float* res = (float*)(ws + 195104768);                       // 256 B

  hipMemsetAsync(flags, 0, 4096, stream);
  prep_kernel<<<16496, 256, 0, stream>>>(wihf, wihb, whhf, whhb, wo, bfv, bbv,
                                         wih_c, whh_c, wout_c, bias_c);
  gather_kernel<<<16384, 64, 0, stream>>>(xw, emb, xbf);
  gemm_xg_kernel<<<dim3(128, 32), 256, 0, stream>>>(xbf, wih_c, bias_c, xg);
  scan_kernel<<<128, 256, 0, stream>>>(whh_c, xg, hfp, hbp, flags);
  logits_kernel<<<256, 256, 0, stream>>>(hfp, hbp, wout_c, bo, y0, lg);
  crf_kernel<<<64, 64, 0, stream>>>(lg, y0, tr, res);
  reduce_kernel<<<1, 64, 0, stream>>>(res, lg + 64);  // res already in ws; write mean below
  // NOTE: reduce writes to d_out, fix call above:
  reduce_kernel<<<1, 64, 0, stream>>>(res, (float*)d_out);
}

// Round 2
// 2331.215 us; speedup vs baseline: 1.2257x; 1.2257x over previous
//
#include <hip/hip_runtime.h>

typedef __attribute__((ext_vector_type(8))) short short8;
typedef __attribute__((ext_vector_type(4))) float f32x4;

#define NEGV -10000.0f

__device__ __forceinline__ float bfu2f(unsigned short u) {
  unsigned int x = ((unsigned int)u) << 16;
  return __builtin_bit_cast(float, x);
}
__device__ __forceinline__ unsigned short f2bfu(float f) {
  unsigned int x = __builtin_bit_cast(unsigned int, f);
  x += 0x7fffu + ((x >> 16) & 1u);
  return (unsigned short)(x >> 16);
}
__device__ __forceinline__ float fsig(float x) {
  return 1.0f / (1.0f + __expf(-x));
}
__device__ __forceinline__ float ftanh(float x) {
  x = fminf(15.0f, fmaxf(-15.0f, x));
  float e = __expf(-2.0f * x);
  return (1.0f - e) / (1.0f + e);
}

// ---------------- prep: convert weights to bf16, build combined bias ----------------
__global__ __launch_bounds__(256) void prep_kernel(
    const float* __restrict__ wihf, const float* __restrict__ wihb,
    const float* __restrict__ whhf, const float* __restrict__ whhb,
    const float* __restrict__ wo, const float* __restrict__ bfv,
    const float* __restrict__ bbv,
    unsigned short* __restrict__ wih_c, unsigned short* __restrict__ whh_c,
    unsigned short* __restrict__ wout_c, float* __restrict__ bias_c) {
  size_t i = (size_t)blockIdx.x * 256 + threadIdx.x;
  const size_t n_half = 2048u * 512u;
  const size_t n_wih = 2u * n_half;
  const size_t n_wo = 24u * 1024u;
  if (i < n_wih) {
    float v = (i < n_half) ? wihf[i] : wihb[i - n_half];
    wih_c[i] = f2bfu(v);
  } else if (i < 2u * n_wih) {
    size_t j = i - n_wih;
    float v = (j < n_half) ? whhf[j] : whhb[j - n_half];
    whh_c[j] = f2bfu(v);
  } else if (i < 2u * n_wih + n_wo) {
    size_t j = i - 2u * n_wih;
    wout_c[j] = f2bfu(wo[j]);
  } else if (i < 2u * n_wih + n_wo + 4096u) {
    size_t j = i - 2u * n_wih - n_wo;
    bias_c[j] = (j < 2048u) ? bfv[j] : bbv[j - 2048u];
  }
}

// ---------------- gather: x_bf16[tb][e] = bf16(emb[xw[tb]][e]) ----------------
__global__ __launch_bounds__(64) void gather_kernel(
    const int* __restrict__ xw, const float* __restrict__ emb,
    unsigned short* __restrict__ xbf) {
  int tb = blockIdx.x;
  int l = threadIdx.x;
  int tok = xw[tb];
  const float* src = emb + (size_t)tok * 512 + l * 8;
  short8 o;
#pragma unroll
  for (int j = 0; j < 8; ++j) o[j] = (short)f2bfu(src[j]);
  *(short8*)(xbf + (size_t)tb * 512 + l * 8) = o;
}

// ---------------- GEMM: xg[16384][4096] = xbf[16384][512] @ wih_c[4096][512]^T + bias ----
__global__ __launch_bounds__(256) void gemm_xg_kernel(
    const unsigned short* __restrict__ A,   // [16384][512]
    const unsigned short* __restrict__ Bm,  // [4096][512]
    const float* __restrict__ bias,         // [4096]
    unsigned short* __restrict__ C) {       // [16384][4096] bf16
  __shared__ alignas(16) char As[16384];
  __shared__ alignas(16) char Bs[16384];
  int m0 = blockIdx.x * 128, n0 = blockIdx.y * 128;
  int tid = threadIdx.x;
  int wv = tid >> 6, l = tid & 63;
  int wm = wv >> 1, wn = wv & 1;
  int col = l & 15, quad = l >> 4;
  f32x4 zero4 = {0.f, 0.f, 0.f, 0.f};
  f32x4 acc[4][4];
#pragma unroll
  for (int i = 0; i < 4; ++i)
#pragma unroll
    for (int j = 0; j < 4; ++j) acc[i][j] = zero4;
  for (int kt = 0; kt < 8; ++kt) {
#pragma unroll
    for (int q = 0; q < 4; ++q) {
      int o = q * 4096 + tid * 16;
      int row = o >> 7;
      int cb = o & 127;
      int swz = cb ^ ((row & 7) << 4);
      short8 va = *(const short8*)(A + (size_t)(m0 + row) * 512 + kt * 64 + (cb >> 1));
      *(short8*)(As + row * 128 + swz) = va;
      short8 vb = *(const short8*)(Bm + (size_t)(n0 + row) * 512 + kt * 64 + (cb >> 1));
      *(short8*)(Bs + row * 128 + swz) = vb;
    }
    __syncthreads();
#pragma unroll
    for (int kk = 0; kk < 2; ++kk) {
      short8 af[4], bf8[4];
#pragma unroll
      for (int mi = 0; mi < 4; ++mi) {
        int r = wm * 64 + mi * 16 + col;
        int cb = kk * 64 + quad * 16;
        af[mi] = *(const short8*)(As + r * 128 + (cb ^ ((r & 7) << 4)));
      }
#pragma unroll
      for (int ni = 0; ni < 4; ++ni) {
        int r = wn * 64 + ni * 16 + col;
        int cb = kk * 64 + quad * 16;
        bf8[ni] = *(const short8*)(Bs + r * 128 + (cb ^ ((r & 7) << 4)));
      }
#pragma unroll
      for (int mi = 0; mi < 4; ++mi)
#pragma unroll
        for (int ni = 0; ni < 4; ++ni)
          acc[mi][ni] = __builtin_amdgcn_mfma_f32_16x16x32_bf16(af[mi], bf8[ni], acc[mi][ni], 0, 0, 0);
    }
    __syncthreads();
  }
#pragma unroll
  for (int ni = 0; ni < 4; ++ni) {
    int cg = n0 + wn * 64 + ni * 16 + col;
    float bv = bias[cg];
#pragma unroll
    for (int mi = 0; mi < 4; ++mi) {
#pragma unroll
      for (int r = 0; r < 4; ++r) {
        int rg = m0 + wm * 64 + mi * 16 + quad * 4 + r;
        C[(size_t)rg * 4096 + cg] = f2bfu(acc[mi][ni][r] + bv);
      }
    }
  }
}

// ---------------- persistent dual-direction LSTM scan ----------------
// 64 wgs, wg g owns units [8g,8g+8) for BOTH directions. All h traffic via
// IF$-coherent (sc0 sc1) accesses: no L2 fences anywhere. Flags: agent-scope
// atomics at IF$. A-fragments loaded global->VGPR directly (each 16B chunk of
// an h plane maps to exactly one lane); no LDS.
// h plane layout: [t][unit_block(64)][b(64)][8 units] bf16 = 64KB/plane.
__global__ __launch_bounds__(256, 1) void scan_kernel(
    const unsigned short* __restrict__ whh,  // [2][2048][512] bf16
    const unsigned short* __restrict__ xg,   // [16384][4096] bf16
    unsigned short* __restrict__ hfp,
    unsigned short* __restrict__ hbp,
    unsigned int* __restrict__ flags) {
  int g = blockIdx.x;
  int u0 = g * 8;
  int tid = threadIdx.x, wv = tid >> 6, l = tid & 63;
  int col = l & 15, quad = l >> 4;
  int b_row = wv * 16 + quad * 4;
  // preload w_hh fragments for both directions (2 dirs x 2 gate-pairs x 16 K-chunks)
  short8 bfr[2][2][16];
#pragma unroll
  for (int dir = 0; dir < 2; ++dir)
#pragma unroll
    for (int n = 0; n < 2; ++n) {
      int blk = n * 2 + (col >> 3);  // 0..3 = i,f,g,o
      int gr = blk * 512 + u0 + (col & 7);
      const unsigned short* base = whh + ((size_t)dir * 2048 + gr) * 512 + quad * 8;
#pragma unroll
      for (int kk = 0; kk < 16; ++kk) bfr[dir][n][kk] = *(const short8*)(base + kk * 32);
    }
  unsigned int* ff = flags;
  unsigned int* bflag = flags + 256;
  float cstf[4] = {0.f, 0.f, 0.f, 0.f};
  float cstb[4] = {0.f, 0.f, 0.f, 0.f};
  f32x4 zero4 = {0.f, 0.f, 0.f, 0.f};
  for (int s = 0; s < 256; ++s) {
    int tf = s, tb = 255 - s;
    // xg prefetch for both chains (plain cacheable loads; xg is read-only)
    float xgf[2][4], xgb[2][4];
#pragma unroll
    for (int n = 0; n < 2; ++n) {
      int gcf = (n * 2 + (col >> 3)) * 512 + u0 + (col & 7);
      int gcb = 2048 + gcf;
#pragma unroll
      for (int r = 0; r < 4; ++r) {
        int b = b_row + r;
        xgf[n][r] = bfu2f(xg[((size_t)tf * 64 + b) * 4096 + gcf]);
        xgb[n][r] = bfu2f(xg[((size_t)tb * 64 + b) * 4096 + gcb]);
      }
    }
    // ================= FWD chain =================
    f32x4 a0 = zero4, a1 = zero4;
    if (s > 0) {
      if (tid == 0)
        while (__hip_atomic_load(ff + (s - 1), __ATOMIC_RELAXED, __HIP_MEMORY_SCOPE_AGENT) < 64u) {}
      __syncthreads();
      const char* pbase = (const char*)hfp + (size_t)(tf - 1) * 65536 + quad * 1024 + (wv * 16 + col) * 16;
      short8 af[16];
#pragma unroll
      for (int kk = 0; kk < 16; ++kk)
        asm volatile("global_load_dwordx4 %0, %1, off sc0 sc1" : "=v"(af[kk]) : "v"(pbase + kk * 4096));
      asm volatile("s_waitcnt vmcnt(0)" ::: "memory");
      __builtin_amdgcn_sched_barrier(0);
#pragma unroll
      for (int kk = 0; kk < 16; ++kk) {
        a0 = __builtin_amdgcn_mfma_f32_16x16x32_bf16(af[kk], bfr[0][0][kk], a0, 0, 0, 0);
        a1 = __builtin_amdgcn_mfma_f32_16x16x32_bf16(af[kk], bfr[0][1][kk], a1, 0, 0, 0);
      }
    }
    {
      unsigned short* dst = hfp + (size_t)tf * 32768 + g * 512;
      bool low = (col < 8);
#pragma unroll
      for (int r = 0; r < 4; ++r) {
        float g0 = a0[r] + xgf[0][r];
        float g1 = a1[r] + xgf[1][r];
        float p0 = __shfl_xor(g0, 8);
        float p1 = __shfl_xor(g1, 8);
        float iv = low ? g0 : p0;
        float fv = low ? p0 : g0;
        float gv = low ? g1 : p1;
        float ov = low ? p1 : g1;
        float cn = fsig(fv) * cstf[r] + fsig(iv) * ftanh(gv);
        cstf[r] = cn;
        float hv = fsig(ov) * ftanh(cn);
        if (low)
          __hip_atomic_store(dst + (b_row + r) * 8 + (col & 7), f2bfu(hv),
                             __ATOMIC_RELAXED, __HIP_MEMORY_SCOPE_AGENT);
      }
    }
    __syncthreads();  // drains vmcnt: all sc1 stores visible at IF$
    if (tid == 0)
      __hip_atomic_fetch_add(ff + s, 1u, __ATOMIC_RELEASE, __HIP_MEMORY_SCOPE_AGENT);
    // ================= BWD chain =================
    f32x4 c0 = zero4, c1 = zero4;
    if (s > 0) {
      if (tid == 0)
        while (__hip_atomic_load(bflag + (s - 1), __ATOMIC_RELAXED, __HIP_MEMORY_SCOPE_AGENT) < 64u) {}
      __syncthreads();
      const char* pbase = (const char*)hbp + (size_t)(tb + 1) * 65536 + quad * 1024 + (wv * 16 + col) * 16;
      short8 af[16];
#pragma unroll
      for (int kk = 0; kk < 16; ++kk)
        asm volatile("global_load_dwordx4 %0, %1, off sc0 sc1" : "=v"(af[kk]) : "v"(pbase + kk * 4096));
      asm volatile("s_waitcnt vmcnt(0)" ::: "memory");
      __builtin_amdgcn_sched_barrier(0);
#pragma unroll
      for (int kk = 0; kk < 16; ++kk) {
        c0 = __builtin_amdgcn_mfma_f32_16x16x32_bf16(af[kk], bfr[1][0][kk], c0, 0, 0, 0);
        c1 = __builtin_amdgcn_mfma_f32_16x16x32_bf16(af[kk], bfr[1][1][kk], c1, 0, 0, 0);
      }
    }
    {
      unsigned short* dst = hbp + (size_t)tb * 32768 + g * 512;
      bool low = (col < 8);
#pragma unroll
      for (int r = 0; r < 4; ++r) {
        float g0 = c0[r] + xgb[0][r];
        float g1 = c1[r] + xgb[1][r];
        float p0 = __shfl_xor(g0, 8);
        float p1 = __shfl_xor(g1, 8);
        float iv = low ? g0 : p0;
        float fv = low ? p0 : g0;
        float gv = low ? g1 : p1;
        float ov = low ? p1 : g1;
        float cn = fsig(fv) * cstb[r] + fsig(iv) * ftanh(gv);
        cstb[r] = cn;
        float hv = fsig(ov) * ftanh(cn);
        if (low)
          __hip_atomic_store(dst + (b_row + r) * 8 + (col & 7), f2bfu(hv),
                             __ATOMIC_RELAXED, __HIP_MEMORY_SCOPE_AGENT);
      }
    }
    __syncthreads();
    if (tid == 0)
      __hip_atomic_fetch_add(bflag + s, 1u, __ATOMIC_RELEASE, __HIP_MEMORY_SCOPE_AGENT);
  }
}

// ---------------- logits[t][b][k] = (hf|hb).w_out[k] + b_out, masked ----------------
__global__ __launch_bounds__(256) void logits_kernel(
    const unsigned short* __restrict__ hfp, const unsigned short* __restrict__ hbp,
    const unsigned short* __restrict__ wout, const float* __restrict__ bout,
    const int* __restrict__ y0, float* __restrict__ lg) {
  int t = blockIdx.x, tid = threadIdx.x;
  int b = tid >> 2, ks = tid & 3;
  int ytag = y0[(t + 1) * 64 + b];
  float mk = (ytag > 0) ? 1.f : 0.f;
  float av[6] = {0.f, 0.f, 0.f, 0.f, 0.f, 0.f};
  const char* pf = (const char*)hfp + (size_t)t * 65536;
  const char* pb = (const char*)hbp + (size_t)t * 65536;
  for (int uc = 0; uc < 64; ++uc) {
    short8 hv = *(const short8*)(pf + uc * 1024 + b * 16);
#pragma unroll
    for (int kk = 0; kk < 6; ++kk) {
      int k = ks * 6 + kk;
      short8 wv = *(const short8*)(wout + (size_t)k * 1024 + uc * 8);
#pragma unroll
      for (int j = 0; j < 8; ++j)
        av[kk] += bfu2f((unsigned short)hv[j]) * bfu2f((unsigned short)wv[j]);
    }
  }
  for (int uc = 0; uc < 64; ++uc) {
    short8 hv = *(const short8*)(pb + uc * 1024 + b * 16);
#pragma unroll
    for (int kk = 0; kk < 6; ++kk) {
      int k = ks * 6 + kk;
      short8 wv = *(const short8*)(wout + (size_t)k * 1024 + 512 + uc * 8);
#pragma unroll
      for (int j = 0; j < 8; ++j)
        av[kk] += bfu2f((unsigned short)hv[j]) * bfu2f((unsigned short)wv[j]);
    }
  }
#pragma unroll
  for (int kk = 0; kk < 6; ++kk) {
    int k = ks * 6 + kk;
    lg[((size_t)t * 64 + b) * 32 + k] = mk * (av[kk] + bout[k]);
  }
}

// ---------------- CRF forward + gold, one wave per batch ----------------
__global__ __launch_bounds__(64) void crf_kernel(
    const float* __restrict__ lg, const int* __restrict__ y0,
    const float* __restrict__ trans, float* __restrict__ res) {
  int b = blockIdx.x, l = threadIdx.x;
  __shared__ float tl[600];
  __shared__ float sc[24];
  for (int i = l; i < 576; i += 64) tl[(i / 24) * 25 + (i % 24)] = trans[i];
  if (l < 24) sc[l] = (l == 1) ? 0.f : NEGV;
  __syncthreads();
  float gold = 0.f;
  int lens = 0;
  for (int t = l; t < 256; t += 64) {
    int y1 = y0[(t + 1) * 64 + b];
    int yp = y0[t * 64 + b];
    if (y1 > 0) {
      gold += lg[((size_t)t * 64 + b) * 32 + y1] + tl[y1 * 25 + yp];
      lens += 1;
    }
  }
#pragma unroll
  for (int off = 32; off > 0; off >>= 1) {
    gold += __shfl_down(gold, off);
    lens += __shfl_down(lens, off);
  }
  gold = __shfl(gold, 0);
  lens = __shfl(lens, 0);
  int last = y0[lens * 64 + b];
  gold += tl[2 * 25 + last];
  int lc = (l < 24) ? l : 23;
  float trow[24];
#pragma unroll
  for (int j = 0; j < 24; ++j) trow[j] = tl[lc * 25 + j];
  for (int t = 0; t < 256; ++t) {
    int y1 = y0[(t + 1) * 64 + b];
    if (y1 > 0) {
      float ns = 0.f;
      if (l < 24) {
        float ht = lg[((size_t)t * 64 + b) * 32 + l];
        float mx = -3.0e38f;
        float sj[24];
#pragma unroll
        for (int j = 0; j < 24; ++j) {
          sj[j] = sc[j] + trow[j];
          mx = fmaxf(mx, sj[j]);
        }
        float sm = 0.f;
#pragma unroll
        for (int j = 0; j < 24; ++j) sm += __expf(sj[j] - mx);
        ns = ht + mx + __logf(sm);
      }
      __syncthreads();
      if (l < 24) sc[l] = ns;
      __syncthreads();
    }
  }
  float v = (l < 24) ? sc[l] + tl[2 * 25 + l] : -3.0e38f;
  float mx = v;
#pragma unroll
  for (int off = 32; off > 0; off >>= 1) mx = fmaxf(mx, __shfl_xor(mx, off));
  float se = (l < 24) ? __expf(v - mx) : 0.f;
#pragma unroll
  for (int off = 32; off > 0; off >>= 1) se += __shfl_xor(se, off);
  float Z = mx + __logf(se);
  if (l == 0) res[b] = Z - gold;
}

__global__ __launch_bounds__(64) void reduce_kernel(const float* __restrict__ res,
                                                    float* __restrict__ out) {
  int l = threadIdx.x;
  float v = res[l];
#pragma unroll
  for (int off = 32; off > 0; off >>= 1) v += __shfl_down(v, off);
  if (l == 0) out[0] = v * (1.0f / 64.0f);
}

extern "C" void kernel_launch(void* const* d_in, const int* in_sizes, int n_in,
                              void* d_out, int out_size, void* d_ws, size_t ws_size,
                              hipStream_t stream) {
  (void)in_sizes; (void)n_in; (void)out_size; (void)ws_size;
  const int* xw = (const int*)d_in[0];
  const int* y0 = (const int*)d_in[1];
  const float* emb = (const float*)d_in[2];
  const float* wihf = (const float*)d_in[3];
  const float* whhf = (const float*)d_in[4];
  const float* bfv = (const float*)d_in[5];
  const float* wihb = (const float*)d_in[6];
  const float* whhb = (const float*)d_in[7];
  const float* bbv = (const float*)d_in[8];
  const float* wo = (const float*)d_in[9];
  const float* bo = (const float*)d_in[10];
  const float* tr = (const float*)d_in[11];
  char* ws = (char*)d_ws;
  unsigned short* xg = (unsigned short*)(ws + 0);              // 134217728 B
  unsigned short* xbf = (unsigned short*)(ws + 134217728);     // 16777216 B
  unsigned short* wih_c = (unsigned short*)(ws + 150994944);   // 4194304 B
  unsigned short* whh_c = (unsigned short*)(ws + 155189248);   // 4194304 B
  unsigned short* wout_c = (unsigned short*)(ws + 159383552);  // 49152 B
  float* bias_c = (float*)(ws + 159432704);                    // 16384 B
  unsigned short* hfp = (unsigned short*)(ws + 159449088);     // 16777216 B
  unsigned short* hbp = (unsigned short*)(ws + 176226304);     // 16777216 B
  float* lg = (float*)(ws + 193003520);                        // 2097152 B
  unsigned int* flags = (unsigned int*)(ws + 195100672);       // 4096 B
  float* res = (float*)(ws + 195104768);                       // 256 B

  hipMemsetAsync(flags, 0, 4096, stream);
  prep_kernel<<<16496, 256, 0, stream>>>(wihf, wihb, whhf, whhb, wo, bfv, bbv,
                                         wih_c, whh_c, wout_c, bias_c);
  gather_kernel<<<16384, 64, 0, stream>>>(xw, emb, xbf);
  gemm_xg_kernel<<<dim3(128, 32), 256, 0, stream>>>(xbf, wih_c, bias_c, xg);
  scan_kernel<<<64, 256, 0, stream>>>(whh_c, xg, hfp, hbp, flags);
  logits_kernel<<<256, 256, 0, stream>>>(hfp, hbp, wout_c, bo, y0, lg);
  crf_kernel<<<64, 64, 0, stream>>>(lg, y0, tr, res);
  reduce_kernel<<<1, 64, 0, stream>>>(res, (float*)d_out);
}

// Round 3
// 1967.332 us; speedup vs baseline: 1.4524x; 1.1850x over previous
//
#include <hip/hip_runtime.h>

typedef __attribute__((ext_vector_type(8))) short short8;
typedef __attribute__((ext_vector_type(4))) float f32x4;

#define NEGV -10000.0f

__device__ __forceinline__ float bfu2f(unsigned short u) {
  unsigned int x = ((unsigned int)u) << 16;
  return __builtin_bit_cast(float, x);
}
__device__ __forceinline__ unsigned short f2bfu(float f) {
  unsigned int x = __builtin_bit_cast(unsigned int, f);
  x += 0x7fffu + ((x >> 16) & 1u);
  return (unsigned short)(x >> 16);
}
__device__ __forceinline__ float fsig(float x) {
  return 1.0f / (1.0f + __expf(-x));
}
__device__ __forceinline__ float ftanh(float x) {
  x = fminf(15.0f, fmaxf(-15.0f, x));
  float e = __expf(-2.0f * x);
  return (1.0f - e) / (1.0f + e);
}

// ---------------- prep: convert weights to bf16, build combined bias ----------------
__global__ __launch_bounds__(256) void prep_kernel(
    const float* __restrict__ wihf, const float* __restrict__ wihb,
    const float* __restrict__ whhf, const float* __restrict__ whhb,
    const float* __restrict__ wo, const float* __restrict__ bfv,
    const float* __restrict__ bbv,
    unsigned short* __restrict__ wih_c, unsigned short* __restrict__ whh_c,
    unsigned short* __restrict__ wout_c, float* __restrict__ bias_c) {
  size_t i = (size_t)blockIdx.x * 256 + threadIdx.x;
  const size_t n_half = 2048u * 512u;
  const size_t n_wih = 2u * n_half;
  const size_t n_wo = 24u * 1024u;
  if (i < n_wih) {
    float v = (i < n_half) ? wihf[i] : wihb[i - n_half];
    wih_c[i] = f2bfu(v);
  } else if (i < 2u * n_wih) {
    size_t j = i - n_wih;
    float v = (j < n_half) ? whhf[j] : whhb[j - n_half];
    whh_c[j] = f2bfu(v);
  } else if (i < 2u * n_wih + n_wo) {
    size_t j = i - 2u * n_wih;
    wout_c[j] = f2bfu(wo[j]);
  } else if (i < 2u * n_wih + n_wo + 4096u) {
    size_t j = i - 2u * n_wih - n_wo;
    bias_c[j] = (j < 2048u) ? bfv[j] : bbv[j - 2048u];
  }
}

// ---------------- gather: x_bf16[tb][e] = bf16(emb[xw[tb]][e]) ----------------
__global__ __launch_bounds__(64) void gather_kernel(
    const int* __restrict__ xw, const float* __restrict__ emb,
    unsigned short* __restrict__ xbf) {
  int tb = blockIdx.x;
  int l = threadIdx.x;
  int tok = xw[tb];
  const float* src = emb + (size_t)tok * 512 + l * 8;
  short8 o;
#pragma unroll
  for (int j = 0; j < 8; ++j) o[j] = (short)f2bfu(src[j]);
  *(short8*)(xbf + (size_t)tb * 512 + l * 8) = o;
}

// ---------------- GEMM: xg[16384][4096] = xbf[16384][512] @ wih_c[4096][512]^T + bias ----
__global__ __launch_bounds__(256) void gemm_xg_kernel(
    const unsigned short* __restrict__ A,   // [16384][512]
    const unsigned short* __restrict__ Bm,  // [4096][512]
    const float* __restrict__ bias,         // [4096]
    unsigned short* __restrict__ C) {       // [16384][4096] bf16
  __shared__ alignas(16) char As[16384];
  __shared__ alignas(16) char Bs[16384];
  int m0 = blockIdx.x * 128, n0 = blockIdx.y * 128;
  int tid = threadIdx.x;
  int wv = tid >> 6, l = tid & 63;
  int wm = wv >> 1, wn = wv & 1;
  int col = l & 15, quad = l >> 4;
  f32x4 zero4 = {0.f, 0.f, 0.f, 0.f};
  f32x4 acc[4][4];
#pragma unroll
  for (int i = 0; i < 4; ++i)
#pragma unroll
    for (int j = 0; j < 4; ++j) acc[i][j] = zero4;
  for (int kt = 0; kt < 8; ++kt) {
#pragma unroll
    for (int q = 0; q < 4; ++q) {
      int o = q * 4096 + tid * 16;
      int row = o >> 7;
      int cb = o & 127;
      int swz = cb ^ ((row & 7) << 4);
      short8 va = *(const short8*)(A + (size_t)(m0 + row) * 512 + kt * 64 + (cb >> 1));
      *(short8*)(As + row * 128 + swz) = va;
      short8 vb = *(const short8*)(Bm + (size_t)(n0 + row) * 512 + kt * 64 + (cb >> 1));
      *(short8*)(Bs + row * 128 + swz) = vb;
    }
    __syncthreads();
#pragma unroll
    for (int kk = 0; kk < 2; ++kk) {
      short8 af[4], bf8[4];
#pragma unroll
      for (int mi = 0; mi < 4; ++mi) {
        int r = wm * 64 + mi * 16 + col;
        int cb = kk * 64 + quad * 16;
        af[mi] = *(const short8*)(As + r * 128 + (cb ^ ((r & 7) << 4)));
      }
#pragma unroll
      for (int ni = 0; ni < 4; ++ni) {
        int r = wn * 64 + ni * 16 + col;
        int cb = kk * 64 + quad * 16;
        bf8[ni] = *(const short8*)(Bs + r * 128 + (cb ^ ((r & 7) << 4)));
      }
#pragma unroll
      for (int mi = 0; mi < 4; ++mi)
#pragma unroll
        for (int ni = 0; ni < 4; ++ni)
          acc[mi][ni] = __builtin_amdgcn_mfma_f32_16x16x32_bf16(af[mi], bf8[ni], acc[mi][ni], 0, 0, 0);
    }
    __syncthreads();
  }
#pragma unroll
  for (int ni = 0; ni < 4; ++ni) {
    int cg = n0 + wn * 64 + ni * 16 + col;
    float bv = bias[cg];
#pragma unroll
    for (int mi = 0; mi < 4; ++mi) {
#pragma unroll
      for (int r = 0; r < 4; ++r) {
        int rg = m0 + wm * 64 + mi * 16 + quad * 4 + r;
        C[(size_t)rg * 4096 + cg] = f2bfu(acc[mi][ni][r] + bv);
      }
    }
  }
}

// ---------------- persistent LSTM scan: fully wave-decoupled ----------------
// 256 wgs x 128 threads = 512 waves. Wave id wid: dir=wid&1, g=(wid>>1)&63,
// wv=(wid>>7)&3. Wave (dir,g,wv) computes h[t][batch wv*16..+16][units 8g..8g+8]
// each step. Dependency cohort: reader (dir,*,wv) needs producers (dir,g',wv)
// only -> 8 independent cohorts of 64 waves. Sync: per-wave flag slot
// flags[dir*256+wv*64+g] (plain sc0sc1 store after vmcnt drain); readers poll
// their 64-slot row lane-parallel with __ballot. No atomics, no __syncthreads.
// h plane layout: [t][g'(64)][b(64)][8 units] bf16 = 64KB/plane, IF$-coherent.
__global__ __launch_bounds__(128, 1) void scan_kernel(
    const unsigned short* __restrict__ whh,  // [2][2048][512] bf16
    const unsigned short* __restrict__ xg,   // [16384][4096] bf16
    unsigned short* __restrict__ hfp,
    unsigned short* __restrict__ hbp,
    unsigned int* __restrict__ flags) {
  int wid = blockIdx.x * 2 + (threadIdx.x >> 6);
  int l = threadIdx.x & 63;
  int dir = wid & 1;
  int g = (wid >> 1) & 63;
  int wv = (wid >> 7) & 3;
  int u0 = g * 8;
  int col = l & 15, quad = l >> 4;
  int b_row = wv * 16 + quad * 4;
  // preload this dir's w_hh fragments: 2 gate-pairs x 16 K-chunks = 128 VGPRs
  short8 bfr[2][16];
#pragma unroll
  for (int n = 0; n < 2; ++n) {
    int blk = n * 2 + (col >> 3);  // 0..3 = i,f,g,o
    int gr = blk * 512 + u0 + (col & 7);
    const unsigned short* base = whh + ((size_t)dir * 2048 + gr) * 512 + quad * 8;
#pragma unroll
    for (int kk = 0; kk < 16; ++kk) bfr[n][kk] = *(const short8*)(base + kk * 32);
  }
  unsigned short* hseq = dir ? hbp : hfp;
  unsigned int* myrow = flags + dir * 256 + wv * 64;
  unsigned int* myslot = myrow + g;
  float cst[4] = {0.f, 0.f, 0.f, 0.f};
  f32x4 zero4 = {0.f, 0.f, 0.f, 0.f};
  for (int s = 0; s < 256; ++s) {
    int t = dir ? (255 - s) : s;
    // xg loads (plain cached, independent of sync -> in flight during poll)
    float xgv[2][4];
#pragma unroll
    for (int n = 0; n < 2; ++n) {
      int gc = dir * 2048 + (n * 2 + (col >> 3)) * 512 + u0 + (col & 7);
#pragma unroll
      for (int r = 0; r < 4; ++r)
        xgv[n][r] = bfu2f(xg[((size_t)t * 64 + b_row + r) * 4096 + gc]);
    }
    f32x4 a0 = zero4, a1 = zero4;
    if (s > 0) {
      int tprev = dir ? (t + 1) : (t - 1);
      unsigned long long bal;
      do {
        unsigned int v = __hip_atomic_load(myrow + l, __ATOMIC_RELAXED, __HIP_MEMORY_SCOPE_AGENT);
        bal = __ballot(v < (unsigned int)s);
      } while (bal != 0ull);
      // bal == 0 here; folding it into the address makes the h loads
      // data-dependent on the final poll (no speculative early serve).
      const char* pbase = (const char*)hseq + (size_t)tprev * 65536 + quad * 1024 +
                          (wv * 16 + col) * 16 + (size_t)(bal & 1ull);
      __builtin_amdgcn_sched_barrier(0);
      short8 af[16];
#pragma unroll
      for (int kk = 0; kk < 16; ++kk)
        asm volatile("global_load_dwordx4 %0, %1, off sc0 sc1" : "=v"(af[kk]) : "v"(pbase + kk * 4096));
      asm volatile("s_waitcnt vmcnt(0)" ::: "memory");
      __builtin_amdgcn_sched_barrier(0);
#pragma unroll
      for (int kk = 0; kk < 16; ++kk) {
        a0 = __builtin_amdgcn_mfma_f32_16x16x32_bf16(af[kk], bfr[0][kk], a0, 0, 0, 0);
        a1 = __builtin_amdgcn_mfma_f32_16x16x32_bf16(af[kk], bfr[1][kk], a1, 0, 0, 0);
      }
    }
    {
      unsigned short* dst = hseq + (size_t)t * 32768 + g * 512;
      bool low = (col < 8);
#pragma unroll
      for (int r = 0; r < 4; ++r) {
        float g0 = a0[r] + xgv[0][r];
        float g1 = a1[r] + xgv[1][r];
        float p0 = __shfl_xor(g0, 8);
        float p1 = __shfl_xor(g1, 8);
        float iv = low ? g0 : p0;
        float fv = low ? p0 : g0;
        float gv = low ? g1 : p1;
        float ov = low ? p1 : g1;
        float cn = fsig(fv) * cst[r] + fsig(iv) * ftanh(gv);
        cst[r] = cn;
        float hv = fsig(ov) * ftanh(cn);
        if (low)
          __hip_atomic_store(dst + (b_row + r) * 8 + (col & 7), f2bfu(hv),
                             __ATOMIC_RELAXED, __HIP_MEMORY_SCOPE_AGENT);
      }
    }
    asm volatile("s_waitcnt vmcnt(0)" ::: "memory");  // h stores ack'd at IF$
    if (l == 0)
      __hip_atomic_store(myslot, (unsigned int)(s + 1), __ATOMIC_RELAXED, __HIP_MEMORY_SCOPE_AGENT);
  }
}

// ---------------- logits[t][b][k] = (hf|hb).w_out[k] + b_out, masked ----------------
__global__ __launch_bounds__(256) void logits_kernel(
    const unsigned short* __restrict__ hfp, const unsigned short* __restrict__ hbp,
    const unsigned short* __restrict__ wout, const float* __restrict__ bout,
    const int* __restrict__ y0, float* __restrict__ lg) {
  int t = blockIdx.x, tid = threadIdx.x;
  int b = tid >> 2, ks = tid & 3;
  int ytag = y0[(t + 1) * 64 + b];
  float mk = (ytag > 0) ? 1.f : 0.f;
  float av[6] = {0.f, 0.f, 0.f, 0.f, 0.f, 0.f};
  const char* pf = (const char*)hfp + (size_t)t * 65536;
  const char* pb = (const char*)hbp + (size_t)t * 65536;
  for (int uc = 0; uc < 64; ++uc) {
    short8 hv = *(const short8*)(pf + uc * 1024 + b * 16);
#pragma unroll
    for (int kk = 0; kk < 6; ++kk) {
      int k = ks * 6 + kk;
      short8 wv = *(const short8*)(wout + (size_t)k * 1024 + uc * 8);
#pragma unroll
      for (int j = 0; j < 8; ++j)
        av[kk] += bfu2f((unsigned short)hv[j]) * bfu2f((unsigned short)wv[j]);
    }
  }
  for (int uc = 0; uc < 64; ++uc) {
    short8 hv = *(const short8*)(pb + uc * 1024 + b * 16);
#pragma unroll
    for (int kk = 0; kk < 6; ++kk) {
      int k = ks * 6 + kk;
      short8 wv = *(const short8*)(wout + (size_t)k * 1024 + 512 + uc * 8);
#pragma unroll
      for (int j = 0; j < 8; ++j)
        av[kk] += bfu2f((unsigned short)hv[j]) * bfu2f((unsigned short)wv[j]);
    }
  }
#pragma unroll
  for (int kk = 0; kk < 6; ++kk) {
    int k = ks * 6 + kk;
    lg[((size_t)t * 64 + b) * 32 + k] = mk * (av[kk] + bout[k]);
  }
}

// ---------------- CRF forward + gold, one wave per batch ----------------
__global__ __launch_bounds__(64) void crf_kernel(
    const float* __restrict__ lg, const int* __restrict__ y0,
    const float* __restrict__ trans, float* __restrict__ res) {
  int b = blockIdx.x, l = threadIdx.x;
  __shared__ float tl[600];
  __shared__ float sc[24];
  for (int i = l; i < 576; i += 64) tl[(i / 24) * 25 + (i % 24)] = trans[i];
  if (l < 24) sc[l] = (l == 1) ? 0.f : NEGV;
  __syncthreads();
  float gold = 0.f;
  int lens = 0;
  for (int t = l; t < 256; t += 64) {
    int y1 = y0[(t + 1) * 64 + b];
    int yp = y0[t * 64 + b];
    if (y1 > 0) {
      gold += lg[((size_t)t * 64 + b) * 32 + y1] + tl[y1 * 25 + yp];
      lens += 1;
    }
  }
#pragma unroll
  for (int off = 32; off > 0; off >>= 1) {
    gold += __shfl_down(gold, off);
    lens += __shfl_down(lens, off);
  }
  gold = __shfl(gold, 0);
  lens = __shfl(lens, 0);
  int last = y0[lens * 64 + b];
  gold += tl[2 * 25 + last];
  int lc = (l < 24) ? l : 23;
  float trow[24];
#pragma unroll
  for (int j = 0; j < 24; ++j) trow[j] = tl[lc * 25 + j];
  for (int t = 0; t < 256; ++t) {
    int y1 = y0[(t + 1) * 64 + b];
    if (y1 > 0) {
      float ns = 0.f;
      if (l < 24) {
        float ht = lg[((size_t)t * 64 + b) * 32 + l];
        float mx = -3.0e38f;
        float sj[24];
#pragma unroll
        for (int j = 0; j < 24; ++j) {
          sj[j] = sc[j] + trow[j];
          mx = fmaxf(mx, sj[j]);
        }
        float sm = 0.f;
#pragma unroll
        for (int j = 0; j < 24; ++j) sm += __expf(sj[j] - mx);
        ns = ht + mx + __logf(sm);
      }
      __syncthreads();
      if (l < 24) sc[l] = ns;
      __syncthreads();
    }
  }
  float v = (l < 24) ? sc[l] + tl[2 * 25 + l] : -3.0e38f;
  float mx = v;
#pragma unroll
  for (int off = 32; off > 0; off >>= 1) mx = fmaxf(mx, __shfl_xor(mx, off));
  float se = (l < 24) ? __expf(v - mx) : 0.f;
#pragma unroll
  for (int off = 32; off > 0; off >>= 1) se += __shfl_xor(se, off);
  float Z = mx + __logf(se);
  if (l == 0) res[b] = Z - gold;
}

__global__ __launch_bounds__(64) void reduce_kernel(const float* __restrict__ res,
                                                    float* __restrict__ out) {
  int l = threadIdx.x;
  float v = res[l];
#pragma unroll
  for (int off = 32; off > 0; off >>= 1) v += __shfl_down(v, off);
  if (l == 0) out[0] = v * (1.0f / 64.0f);
}

extern "C" void kernel_launch(void* const* d_in, const int* in_sizes, int n_in,
                              void* d_out, int out_size, void* d_ws, size_t ws_size,
                              hipStream_t stream) {
  (void)in_sizes; (void)n_in; (void)out_size; (void)ws_size;
  const int* xw = (const int*)d_in[0];
  const int* y0 = (const int*)d_in[1];
  const float* emb = (const float*)d_in[2];
  const float* wihf = (const float*)d_in[3];
  const float* whhf = (const float*)d_in[4];
  const float* bfv = (const float*)d_in[5];
  const float* wihb = (const float*)d_in[6];
  const float* whhb = (const float*)d_in[7];
  const float* bbv = (const float*)d_in[8];
  const float* wo = (const float*)d_in[9];
  const float* bo = (const float*)d_in[10];
  const float* tr = (const float*)d_in[11];
  char* ws = (char*)d_ws;
  unsigned short* xg = (unsigned short*)(ws + 0);              // 134217728 B
  unsigned short* xbf = (unsigned short*)(ws + 134217728);     // 16777216 B
  unsigned short* wih_c = (unsigned short*)(ws + 150994944);   // 4194304 B
  unsigned short* whh_c = (unsigned short*)(ws + 155189248);   // 4194304 B
  unsigned short* wout_c = (unsigned short*)(ws + 159383552);  // 49152 B
  float* bias_c = (float*)(ws + 159432704);                    // 16384 B
  unsigned short* hfp = (unsigned short*)(ws + 159449088);     // 16777216 B
  unsigned short* hbp = (unsigned short*)(ws + 176226304);     // 16777216 B
  float* lg = (float*)(ws + 193003520);                        // 2097152 B
  unsigned int* flags = (unsigned int*)(ws + 195100672);       // 4096 B
  float* res = (float*)(ws + 195104768);                       // 256 B

  hipMemsetAsync(flags, 0, 4096, stream);
  prep_kernel<<<16496, 256, 0, stream>>>(wihf, wihb, whhf, whhb, wo, bfv, bbv,
                                         wih_c, whh_c, wout_c, bias_c);
  gather_kernel<<<16384, 64, 0, stream>>>(xw, emb, xbf);
  gemm_xg_kernel<<<dim3(128, 32), 256, 0, stream>>>(xbf, wih_c, bias_c, xg);
  scan_kernel<<<256, 128, 0, stream>>>(whh_c, xg, hfp, hbp, flags);
  logits_kernel<<<256, 256, 0, stream>>>(hfp, hbp, wout_c, bo, y0, lg);
  crf_kernel<<<64, 64, 0, stream>>>(lg, y0, tr, res);
  reduce_kernel<<<1, 64, 0, stream>>>(res, (float*)d_out);
}

// Round 4
// 1562.775 us; speedup vs baseline: 1.8283x; 1.2589x over previous
//
#include <hip/hip_runtime.h>

typedef __attribute__((ext_vector_type(8))) short short8;
typedef __attribute__((ext_vector_type(4))) float f32x4;

#define NEGV -10000.0f

__device__ __forceinline__ float bfu2f(unsigned short u) {
  unsigned int x = ((unsigned int)u) << 16;
  return __builtin_bit_cast(float, x);
}
__device__ __forceinline__ unsigned short f2bfu(float f) {
  unsigned int x = __builtin_bit_cast(unsigned int, f);
  x += 0x7fffu + ((x >> 16) & 1u);
  return (unsigned short)(x >> 16);
}
__device__ __forceinline__ float fsig(float x) {
  return 1.0f / (1.0f + __expf(-x));
}
__device__ __forceinline__ float ftanh(float x) {
  x = fminf(15.0f, fmaxf(-15.0f, x));
  float e = __expf(-2.0f * x);
  return (1.0f - e) / (1.0f + e);
}

// ---------------- prep: convert weights to bf16, build combined bias ----------------
__global__ __launch_bounds__(256) void prep_kernel(
    const float* __restrict__ wihf, const float* __restrict__ wihb,
    const float* __restrict__ whhf, const float* __restrict__ whhb,
    const float* __restrict__ wo, const float* __restrict__ bfv,
    const float* __restrict__ bbv,
    unsigned short* __restrict__ wih_c, unsigned short* __restrict__ whh_c,
    unsigned short* __restrict__ wout_c, float* __restrict__ bias_c) {
  size_t i = (size_t)blockIdx.x * 256 + threadIdx.x;
  const size_t n_half = 2048u * 512u;
  const size_t n_wih = 2u * n_half;
  const size_t n_wo = 24u * 1024u;
  if (i < n_wih) {
    float v = (i < n_half) ? wihf[i] : wihb[i - n_half];
    wih_c[i] = f2bfu(v);
  } else if (i < 2u * n_wih) {
    size_t j = i - n_wih;
    float v = (j < n_half) ? whhf[j] : whhb[j - n_half];
    whh_c[j] = f2bfu(v);
  } else if (i < 2u * n_wih + n_wo) {
    size_t j = i - 2u * n_wih;
    wout_c[j] = f2bfu(wo[j]);
  } else if (i < 2u * n_wih + n_wo + 4096u) {
    size_t j = i - 2u * n_wih - n_wo;
    bias_c[j] = (j < 2048u) ? bfv[j] : bbv[j - 2048u];
  }
}

// ---------------- gather: x_bf16[tb][e] = bf16(emb[xw[tb]][e]) ----------------
__global__ __launch_bounds__(64) void gather_kernel(
    const int* __restrict__ xw, const float* __restrict__ emb,
    unsigned short* __restrict__ xbf) {
  int tb = blockIdx.x;
  int l = threadIdx.x;
  int tok = xw[tb];
  const float* src = emb + (size_t)tok * 512 + l * 8;
  short8 o;
#pragma unroll
  for (int j = 0; j < 8; ++j) o[j] = (short)f2bfu(src[j]);
  *(short8*)(xbf + (size_t)tb * 512 + l * 8) = o;
}

// ---------------- GEMM: xg[16384][4096] = xbf[16384][512] @ wih_c[4096][512]^T + bias ----
__global__ __launch_bounds__(256) void gemm_xg_kernel(
    const unsigned short* __restrict__ A,   // [16384][512]
    const unsigned short* __restrict__ Bm,  // [4096][512]
    const float* __restrict__ bias,         // [4096]
    unsigned short* __restrict__ C) {       // [16384][4096] bf16
  __shared__ alignas(16) char As[16384];
  __shared__ alignas(16) char Bs[16384];
  int m0 = blockIdx.x * 128, n0 = blockIdx.y * 128;
  int tid = threadIdx.x;
  int wv = tid >> 6, l = tid & 63;
  int wm = wv >> 1, wn = wv & 1;
  int col = l & 15, quad = l >> 4;
  f32x4 zero4 = {0.f, 0.f, 0.f, 0.f};
  f32x4 acc[4][4];
#pragma unroll
  for (int i = 0; i < 4; ++i)
#pragma unroll
    for (int j = 0; j < 4; ++j) acc[i][j] = zero4;
  for (int kt = 0; kt < 8; ++kt) {
#pragma unroll
    for (int q = 0; q < 4; ++q) {
      int o = q * 4096 + tid * 16;
      int row = o >> 7;
      int cb = o & 127;
      int swz = cb ^ ((row & 7) << 4);
      short8 va = *(const short8*)(A + (size_t)(m0 + row) * 512 + kt * 64 + (cb >> 1));
      *(short8*)(As + row * 128 + swz) = va;
      short8 vb = *(const short8*)(Bm + (size_t)(n0 + row) * 512 + kt * 64 + (cb >> 1));
      *(short8*)(Bs + row * 128 + swz) = vb;
    }
    __syncthreads();
#pragma unroll
    for (int kk = 0; kk < 2; ++kk) {
      short8 af[4], bf8[4];
#pragma unroll
      for (int mi = 0; mi < 4; ++mi) {
        int r = wm * 64 + mi * 16 + col;
        int cb = kk * 64 + quad * 16;
        af[mi] = *(const short8*)(As + r * 128 + (cb ^ ((r & 7) << 4)));
      }
#pragma unroll
      for (int ni = 0; ni < 4; ++ni) {
        int r = wn * 64 + ni * 16 + col;
        int cb = kk * 64 + quad * 16;
        bf8[ni] = *(const short8*)(Bs + r * 128 + (cb ^ ((r & 7) << 4)));
      }
#pragma unroll
      for (int mi = 0; mi < 4; ++mi)
#pragma unroll
        for (int ni = 0; ni < 4; ++ni)
          acc[mi][ni] = __builtin_amdgcn_mfma_f32_16x16x32_bf16(af[mi], bf8[ni], acc[mi][ni], 0, 0, 0);
    }
    __syncthreads();
  }
#pragma unroll
  for (int ni = 0; ni < 4; ++ni) {
    int cg = n0 + wn * 64 + ni * 16 + col;
    float bv = bias[cg];
#pragma unroll
    for (int mi = 0; mi < 4; ++mi) {
#pragma unroll
      for (int r = 0; r < 4; ++r) {
        int rg = m0 + wm * 64 + mi * 16 + quad * 4 + r;
        C[(size_t)rg * 4096 + cg] = f2bfu(acc[mi][ni][r] + bv);
      }
    }
  }
}

// ---------------- persistent LSTM scan: wave-decoupled, 1 wave per wg ----------------
// 512 wgs x 64 threads. Wave wid: dir=wid&1, g=(wid>>1)&63, wv=(wid>>7)&3.
// Weights asm-loaded -> non-rematerializable -> resident in VGPRs (128).
// h store: LDS transpose (256B, single wave, no barrier) -> 16 lanes x 16B
// coalesced sc1 store. Per-wave flag slot, lane-parallel __ballot poll.
__global__ __launch_bounds__(64, 1) void scan_kernel(
    const unsigned short* __restrict__ whh,  // [2][2048][512] bf16
    const unsigned short* __restrict__ xg,   // [16384][4096] bf16
    unsigned short* __restrict__ hfp,
    unsigned short* __restrict__ hbp,
    unsigned int* __restrict__ flags) {
  __shared__ alignas(16) unsigned short tbuf[128];  // 256B transpose scratch
  int wid = blockIdx.x;
  int l = threadIdx.x;
  int dir = wid & 1;
  int g = (wid >> 1) & 63;
  int wv = (wid >> 7) & 3;
  int u0 = g * 8;
  int col = l & 15, quad = l >> 4;
  int b_row = wv * 16 + quad * 4;
  // asm-resident w_hh fragments: 2 gate-pairs x 16 K-chunks = 128 VGPRs
  short8 bfr[2][16];
#pragma unroll
  for (int n = 0; n < 2; ++n) {
    int blk = n * 2 + (col >> 3);  // 0..3 = i,f,g,o
    int gr = blk * 512 + u0 + (col & 7);
    const char* base = (const char*)(whh + ((size_t)dir * 2048 + gr) * 512 + quad * 8);
#pragma unroll
    for (int kk = 0; kk < 16; ++kk)
      asm volatile("global_load_dwordx4 %0, %1, off" : "=v"(bfr[n][kk]) : "v"(base + kk * 64));
  }
  asm volatile("s_waitcnt vmcnt(0)" ::: "memory");
  unsigned short* hseq = dir ? hbp : hfp;
  unsigned int* myrow = flags + dir * 256 + wv * 64;
  unsigned int* myslot = myrow + g;
  float cst[4] = {0.f, 0.f, 0.f, 0.f};
  f32x4 zero4 = {0.f, 0.f, 0.f, 0.f};
  for (int s = 0; s < 256; ++s) {
    int t = dir ? (255 - s) : s;
    // xg loads: independent of sync, in flight during poll
    float xgv[2][4];
#pragma unroll
    for (int n = 0; n < 2; ++n) {
      int gc = dir * 2048 + (n * 2 + (col >> 3)) * 512 + u0 + (col & 7);
#pragma unroll
      for (int r = 0; r < 4; ++r)
        xgv[n][r] = bfu2f(xg[((size_t)t * 64 + b_row + r) * 4096 + gc]);
    }
    f32x4 a0 = zero4, a1 = zero4;
    if (s > 0) {
      int tprev = dir ? (t + 1) : (t - 1);
      unsigned long long bal;
      do {
        unsigned int v = __hip_atomic_load(myrow + l, __ATOMIC_RELAXED, __HIP_MEMORY_SCOPE_AGENT);
        bal = __ballot(v < (unsigned int)s);
      } while (bal != 0ull);
      // bal==0; folding into the address makes h loads data-dependent on the poll
      const char* pbase = (const char*)hseq + (size_t)tprev * 65536 + quad * 1024 +
                          (wv * 16 + col) * 16 + (size_t)(bal & 1ull);
      __builtin_amdgcn_sched_barrier(0);
      short8 af[16];
#pragma unroll
      for (int kk = 0; kk < 16; ++kk)
        asm volatile("global_load_dwordx4 %0, %1, off sc0 sc1" : "=v"(af[kk]) : "v"(pbase + kk * 4096));
      asm volatile("s_waitcnt vmcnt(0)" ::: "memory");
      __builtin_amdgcn_sched_barrier(0);
#pragma unroll
      for (int kk = 0; kk < 16; ++kk) {
        a0 = __builtin_amdgcn_mfma_f32_16x16x32_bf16(af[kk], bfr[0][kk], a0, 0, 0, 0);
        a1 = __builtin_amdgcn_mfma_f32_16x16x32_bf16(af[kk], bfr[1][kk], a1, 0, 0, 0);
      }
    }
    // gates; low/high lane pairs compute identical h, low lanes write LDS
    {
      bool low = (col < 8);
#pragma unroll
      for (int r = 0; r < 4; ++r) {
        float g0 = a0[r] + xgv[0][r];
        float g1 = a1[r] + xgv[1][r];
        float p0 = __shfl_xor(g0, 8);
        float p1 = __shfl_xor(g1, 8);
        float iv = low ? g0 : p0;
        float fv = low ? p0 : g0;
        float gv = low ? g1 : p1;
        float ov = low ? p1 : g1;
        float cn = fsig(fv) * cst[r] + fsig(iv) * ftanh(gv);
        cst[r] = cn;
        float hv = fsig(ov) * ftanh(cn);
        if (low) tbuf[(quad * 4 + r) * 8 + (col & 7)] = f2bfu(hv);
      }
    }
    // wave-internal transpose readback (same wave: lgkmcnt suffices, no barrier)
    asm volatile("s_waitcnt lgkmcnt(0)" ::: "memory");
    if (l < 16) {
      short8 hrow = *(const short8*)(tbuf + l * 8);
      char* dst = (char*)hseq + (size_t)t * 65536 + g * 1024 + (wv * 16 + l) * 16;
      asm volatile("global_store_dwordx4 %0, %1, off sc0 sc1" :: "v"(dst), "v"(hrow) : "memory");
    }
    asm volatile("s_waitcnt vmcnt(0)" ::: "memory");  // h stores ack'd at IF$
    if (l == 0)
      __hip_atomic_store(myslot, (unsigned int)(s + 1), __ATOMIC_RELAXED, __HIP_MEMORY_SCOPE_AGENT);
  }
}

// ---------------- logits[t][b][k] = (hf|hb).w_out[k] + b_out, masked ----------------
__global__ __launch_bounds__(256) void logits_kernel(
    const unsigned short* __restrict__ hfp, const unsigned short* __restrict__ hbp,
    const unsigned short* __restrict__ wout, const float* __restrict__ bout,
    const int* __restrict__ y0, float* __restrict__ lg) {
  int t = blockIdx.x, tid = threadIdx.x;
  int b = tid >> 2, ks = tid & 3;
  int ytag = y0[(t + 1) * 64 + b];
  float mk = (ytag > 0) ? 1.f : 0.f;
  float av[6] = {0.f, 0.f, 0.f, 0.f, 0.f, 0.f};
  const char* pf = (const char*)hfp + (size_t)t * 65536;
  const char* pb = (const char*)hbp + (size_t)t * 65536;
  for (int uc = 0; uc < 64; ++uc) {
    short8 hv = *(const short8*)(pf + uc * 1024 + b * 16);
#pragma unroll
    for (int kk = 0; kk < 6; ++kk) {
      int k = ks * 6 + kk;
      short8 wv = *(const short8*)(wout + (size_t)k * 1024 + uc * 8);
#pragma unroll
      for (int j = 0; j < 8; ++j)
        av[kk] += bfu2f((unsigned short)hv[j]) * bfu2f((unsigned short)wv[j]);
    }
  }
  for (int uc = 0; uc < 64; ++uc) {
    short8 hv = *(const short8*)(pb + uc * 1024 + b * 16);
#pragma unroll
    for (int kk = 0; kk < 6; ++kk) {
      int k = ks * 6 + kk;
      short8 wv = *(const short8*)(wout + (size_t)k * 1024 + 512 + uc * 8);
#pragma unroll
      for (int j = 0; j < 8; ++j)
        av[kk] += bfu2f((unsigned short)hv[j]) * bfu2f((unsigned short)wv[j]);
    }
  }
#pragma unroll
  for (int kk = 0; kk < 6; ++kk) {
    int k = ks * 6 + kk;
    lg[((size_t)t * 64 + b) * 32 + k] = mk * (av[kk] + bout[k]);
  }
}

// ---------------- CRF forward + gold, one wave per batch ----------------
__global__ __launch_bounds__(64) void crf_kernel(
    const float* __restrict__ lg, const int* __restrict__ y0,
    const float* __restrict__ trans, float* __restrict__ res) {
  int b = blockIdx.x, l = threadIdx.x;
  __shared__ float tl[600];
  __shared__ float sc[24];
  for (int i = l; i < 576; i += 64) tl[(i / 24) * 25 + (i % 24)] = trans[i];
  if (l < 24) sc[l] = (l == 1) ? 0.f : NEGV;
  __syncthreads();
  float gold = 0.f;
  int lens = 0;
  for (int t = l; t < 256; t += 64) {
    int y1 = y0[(t + 1) * 64 + b];
    int yp = y0[t * 64 + b];
    if (y1 > 0) {
      gold += lg[((size_t)t * 64 + b) * 32 + y1] + tl[y1 * 25 + yp];
      lens += 1;
    }
  }
#pragma unroll
  for (int off = 32; off > 0; off >>= 1) {
    gold += __shfl_down(gold, off);
    lens += __shfl_down(lens, off);
  }
  gold = __shfl(gold, 0);
  lens = __shfl(lens, 0);
  int last = y0[lens * 64 + b];
  gold += tl[2 * 25 + last];
  int lc = (l < 24) ? l : 23;
  float trow[24];
#pragma unroll
  for (int j = 0; j < 24; ++j) trow[j] = tl[lc * 25 + j];
  for (int t = 0; t < 256; ++t) {
    int y1 = y0[(t + 1) * 64 + b];
    if (y1 > 0) {
      float ns = 0.f;
      if (l < 24) {
        float ht = lg[((size_t)t * 64 + b) * 32 + l];
        float mx = -3.0e38f;
        float sj[24];
#pragma unroll
        for (int j = 0; j < 24; ++j) {
          sj[j] = sc[j] + trow[j];
          mx = fmaxf(mx, sj[j]);
        }
        float sm = 0.f;
#pragma unroll
        for (int j = 0; j < 24; ++j) sm += __expf(sj[j] - mx);
        ns = ht + mx + __logf(sm);
      }
      __syncthreads();
      if (l < 24) sc[l] = ns;
      __syncthreads();
    }
  }
  float v = (l < 24) ? sc[l] + tl[2 * 25 + l] : -3.0e38f;
  float mx = v;
#pragma unroll
  for (int off = 32; off > 0; off >>= 1) mx = fmaxf(mx, __shfl_xor(mx, off));
  float se = (l < 24) ? __expf(v - mx) : 0.f;
#pragma unroll
  for (int off = 32; off > 0; off >>= 1) se += __shfl_xor(se, off);
  float Z = mx + __logf(se);
  if (l == 0) res[b] = Z - gold;
}

__global__ __launch_bounds__(64) void reduce_kernel(const float* __restrict__ res,
                                                    float* __restrict__ out) {
  int l = threadIdx.x;
  float v = res[l];
#pragma unroll
  for (int off = 32; off > 0; off >>= 1) v += __shfl_down(v, off);
  if (l == 0) out[0] = v * (1.0f / 64.0f);
}

extern "C" void kernel_launch(void* const* d_in, const int* in_sizes, int n_in,
                              void* d_out, int out_size, void* d_ws, size_t ws_size,
                              hipStream_t stream) {
  (void)in_sizes; (void)n_in; (void)out_size; (void)ws_size;
  const int* xw = (const int*)d_in[0];
  const int* y0 = (const int*)d_in[1];
  const float* emb = (const float*)d_in[2];
  const float* wihf = (const float*)d_in[3];
  const float* whhf = (const float*)d_in[4];
  const float* bfv = (const float*)d_in[5];
  const float* wihb = (const float*)d_in[6];
  const float* whhb = (const float*)d_in[7];
  const float* bbv = (const float*)d_in[8];
  const float* wo = (const float*)d_in[9];
  const float* bo = (const float*)d_in[10];
  const float* tr = (const float*)d_in[11];
  char* ws = (char*)d_ws;
  unsigned short* xg = (unsigned short*)(ws + 0);              // 134217728 B
  unsigned short* xbf = (unsigned short*)(ws + 134217728);     // 16777216 B
  unsigned short* wih_c = (unsigned short*)(ws + 150994944);   // 4194304 B
  unsigned short* whh_c = (unsigned short*)(ws + 155189248);   // 4194304 B
  unsigned short* wout_c = (unsigned short*)(ws + 159383552);  // 49152 B
  float* bias_c = (float*)(ws + 159432704);                    // 16384 B
  unsigned short* hfp = (unsigned short*)(ws + 159449088);     // 16777216 B
  unsigned short* hbp = (unsigned short*)(ws + 176226304);     // 16777216 B
  float* lg = (float*)(ws + 193003520);                        // 2097152 B
  unsigned int* flags = (unsigned int*)(ws + 195100672);       // 4096 B
  float* res = (float*)(ws + 195104768);                       // 256 B

  hipMemsetAsync(flags, 0, 4096, stream);
  prep_kernel<<<16496, 256, 0, stream>>>(wihf, wihb, whhf, whhb, wo, bfv, bbv,
                                         wih_c, whh_c, wout_c, bias_c);
  gather_kernel<<<16384, 64, 0, stream>>>(xw, emb, xbf);
  gemm_xg_kernel<<<dim3(128, 32), 256, 0, stream>>>(xbf, wih_c, bias_c, xg);
  scan_kernel<<<512, 64, 0, stream>>>(whh_c, xg, hfp, hbp, flags);
  logits_kernel<<<256, 256, 0, stream>>>(hfp, hbp, wout_c, bo, y0, lg);
  crf_kernel<<<64, 64, 0, stream>>>(lg, y0, tr, res);
  reduce_kernel<<<1, 64, 0, stream>>>(res, (float*)d_out);
}

// Round 5
// 1250.170 us; speedup vs baseline: 2.2855x; 1.2500x over previous
//
#include <hip/hip_runtime.h>

typedef __attribute__((ext_vector_type(8))) short short8;
typedef __attribute__((ext_vector_type(4))) float f32x4;

#define NEGV -10000.0f

__device__ __forceinline__ float bfu2f(unsigned short u) {
  unsigned int x = ((unsigned int)u) << 16;
  return __builtin_bit_cast(float, x);
}
__device__ __forceinline__ unsigned short f2bfu(float f) {
  unsigned int x = __builtin_bit_cast(unsigned int, f);
  x += 0x7fffu + ((x >> 16) & 1u);
  return (unsigned short)(x >> 16);
}
__device__ __forceinline__ float fsig(float x) {
  return 1.0f / (1.0f + __expf(-x));
}
__device__ __forceinline__ float ftanh(float x) {
  x = fminf(15.0f, fmaxf(-15.0f, x));
  float e = __expf(-2.0f * x);
  return (1.0f - e) / (1.0f + e);
}

// ---------------- prep: convert weights to bf16, build combined bias ----------------
__global__ __launch_bounds__(256) void prep_kernel(
    const float* __restrict__ wihf, const float* __restrict__ wihb,
    const float* __restrict__ whhf, const float* __restrict__ whhb,
    const float* __restrict__ wo, const float* __restrict__ bfv,
    const float* __restrict__ bbv,
    unsigned short* __restrict__ wih_c, unsigned short* __restrict__ whh_c,
    unsigned short* __restrict__ wout_c, float* __restrict__ bias_c) {
  size_t i = (size_t)blockIdx.x * 256 + threadIdx.x;
  const size_t n_half = 2048u * 512u;
  const size_t n_wih = 2u * n_half;
  const size_t n_wo = 24u * 1024u;
  if (i < n_wih) {
    float v = (i < n_half) ? wihf[i] : wihb[i - n_half];
    wih_c[i] = f2bfu(v);
  } else if (i < 2u * n_wih) {
    size_t j = i - n_wih;
    float v = (j < n_half) ? whhf[j] : whhb[j - n_half];
    whh_c[j] = f2bfu(v);
  } else if (i < 2u * n_wih + n_wo) {
    size_t j = i - 2u * n_wih;
    wout_c[j] = f2bfu(wo[j]);
  } else if (i < 2u * n_wih + n_wo + 4096u) {
    size_t j = i - 2u * n_wih - n_wo;
    bias_c[j] = (j < 2048u) ? bfv[j] : bbv[j - 2048u];
  }
}

// ---------------- gather: x_bf16[tb][e] = bf16(emb[xw[tb]][e]) ----------------
__global__ __launch_bounds__(64) void gather_kernel(
    const int* __restrict__ xw, const float* __restrict__ emb,
    unsigned short* __restrict__ xbf) {
  int tb = blockIdx.x;
  int l = threadIdx.x;
  int tok = xw[tb];
  const float* src = emb + (size_t)tok * 512 + l * 8;
  short8 o;
#pragma unroll
  for (int j = 0; j < 8; ++j) o[j] = (short)f2bfu(src[j]);
  *(short8*)(xbf + (size_t)tb * 512 + l * 8) = o;
}

// ---------------- GEMM: xg[16384][4096] = xbf[16384][512] @ wih_c[4096][512]^T + bias ----
__global__ __launch_bounds__(256) void gemm_xg_kernel(
    const unsigned short* __restrict__ A,   // [16384][512]
    const unsigned short* __restrict__ Bm,  // [4096][512]
    const float* __restrict__ bias,         // [4096]
    unsigned short* __restrict__ C) {       // [16384][4096] bf16
  __shared__ alignas(16) char As[16384];
  __shared__ alignas(16) char Bs[16384];
  int m0 = blockIdx.x * 128, n0 = blockIdx.y * 128;
  int tid = threadIdx.x;
  int wv = tid >> 6, l = tid & 63;
  int wm = wv >> 1, wn = wv & 1;
  int col = l & 15, quad = l >> 4;
  f32x4 zero4 = {0.f, 0.f, 0.f, 0.f};
  f32x4 acc[4][4];
#pragma unroll
  for (int i = 0; i < 4; ++i)
#pragma unroll
    for (int j = 0; j < 4; ++j) acc[i][j] = zero4;
  for (int kt = 0; kt < 8; ++kt) {
#pragma unroll
    for (int q = 0; q < 4; ++q) {
      int o = q * 4096 + tid * 16;
      int row = o >> 7;
      int cb = o & 127;
      int swz = cb ^ ((row & 7) << 4);
      short8 va = *(const short8*)(A + (size_t)(m0 + row) * 512 + kt * 64 + (cb >> 1));
      *(short8*)(As + row * 128 + swz) = va;
      short8 vb = *(const short8*)(Bm + (size_t)(n0 + row) * 512 + kt * 64 + (cb >> 1));
      *(short8*)(Bs + row * 128 + swz) = vb;
    }
    __syncthreads();
#pragma unroll
    for (int kk = 0; kk < 2; ++kk) {
      short8 af[4], bf8[4];
#pragma unroll
      for (int mi = 0; mi < 4; ++mi) {
        int r = wm * 64 + mi * 16 + col;
        int cb = kk * 64 + quad * 16;
        af[mi] = *(const short8*)(As + r * 128 + (cb ^ ((r & 7) << 4)));
      }
#pragma unroll
      for (int ni = 0; ni < 4; ++ni) {
        int r = wn * 64 + ni * 16 + col;
        int cb = kk * 64 + quad * 16;
        bf8[ni] = *(const short8*)(Bs + r * 128 + (cb ^ ((r & 7) << 4)));
      }
#pragma unroll
      for (int mi = 0; mi < 4; ++mi)
#pragma unroll
        for (int ni = 0; ni < 4; ++ni)
          acc[mi][ni] = __builtin_amdgcn_mfma_f32_16x16x32_bf16(af[mi], bf8[ni], acc[mi][ni], 0, 0, 0);
    }
    __syncthreads();
  }
#pragma unroll
  for (int ni = 0; ni < 4; ++ni) {
    int cg = n0 + wn * 64 + ni * 16 + col;
    float bv = bias[cg];
#pragma unroll
    for (int mi = 0; mi < 4; ++mi) {
#pragma unroll
      for (int r = 0; r < 4; ++r) {
        int rg = m0 + wm * 64 + mi * 16 + quad * 4 + r;
        C[(size_t)rg * 4096 + cg] = f2bfu(acc[mi][ni][r] + bv);
      }
    }
  }
}

// ---------------- persistent LSTM scan: wave-decoupled, poll-on-data ----------------
// 512 wgs x 64 threads. Wave wid: dir=wid&1, g=(wid>>1)&63, wv=(wid>>7)&3.
// h planes pre-poisoned to 0xFFFF (bf16 NaN, unreachable: |h|<1). The data IS
// the flag: producers store 16B chunks (atomic at IF$) with sc0 sc1 and no
// drain; readers re-issue their 16 h-loads until no chunk starts with the
// sentinel. One IF$ round trip per step instead of four.
// h plane layout: [t][g'(64)][b(64)][8 units] bf16 = 64KB/plane.
__global__ __launch_bounds__(64, 1) void scan_kernel(
    const unsigned short* __restrict__ whh,  // [2][2048][512] bf16
    const unsigned short* __restrict__ xg,   // [16384][4096] bf16
    unsigned short* __restrict__ hfp,
    unsigned short* __restrict__ hbp) {
  __shared__ alignas(16) unsigned short tbuf[128];  // 256B transpose scratch
  int wid = blockIdx.x;
  int l = threadIdx.x;
  int dir = wid & 1;
  int g = (wid >> 1) & 63;
  int wv = (wid >> 7) & 3;
  int u0 = g * 8;
  int col = l & 15, quad = l >> 4;
  int b_row = wv * 16 + quad * 4;
  // asm-resident w_hh fragments: 2 gate-pairs x 16 K-chunks = 128 VGPRs
  short8 bfr[2][16];
#pragma unroll
  for (int n = 0; n < 2; ++n) {
    int blk = n * 2 + (col >> 3);  // 0..3 = i,f,g,o
    int gr = blk * 512 + u0 + (col & 7);
    const char* base = (const char*)(whh + ((size_t)dir * 2048 + gr) * 512 + quad * 8);
#pragma unroll
    for (int kk = 0; kk < 16; ++kk)
      asm volatile("global_load_dwordx4 %0, %1, off" : "=v"(bfr[n][kk]) : "v"(base + kk * 64));
  }
  asm volatile("s_waitcnt vmcnt(0)" ::: "memory");
  unsigned short* hseq = dir ? hbp : hfp;
  float cst[4] = {0.f, 0.f, 0.f, 0.f};
  f32x4 zero4 = {0.f, 0.f, 0.f, 0.f};
  for (int s = 0; s < 256; ++s) {
    int t = dir ? (255 - s) : s;
    // xg loads: plain cached, issued before the poll -> latency hidden
    float xgv[2][4];
#pragma unroll
    for (int n = 0; n < 2; ++n) {
      int gc = dir * 2048 + (n * 2 + (col >> 3)) * 512 + u0 + (col & 7);
#pragma unroll
      for (int r = 0; r < 4; ++r)
        xgv[n][r] = bfu2f(xg[((size_t)t * 64 + b_row + r) * 4096 + gc]);
    }
    f32x4 a0 = zero4, a1 = zero4;
    if (s > 0) {
      int tprev = dir ? (t + 1) : (t - 1);
      const char* pbase = (const char*)hseq + (size_t)tprev * 65536 + quad * 1024 +
                          (wv * 16 + col) * 16;
      short8 af[16];
      unsigned long long bal;
      do {
#pragma unroll
        for (int kk = 0; kk < 16; ++kk)
          asm volatile("global_load_dwordx4 %0, %1, off sc0 sc1" : "=v"(af[kk]) : "v"(pbase + kk * 4096));
        asm volatile("s_waitcnt vmcnt(0)" ::: "memory");
        unsigned int anystale = 0u;
#pragma unroll
        for (int kk = 0; kk < 16; ++kk)
          anystale |= (((unsigned short)af[kk][0]) == 0xFFFFu) ? 1u : 0u;
        bal = __ballot(anystale != 0u);
      } while (bal != 0ull);
      __builtin_amdgcn_sched_barrier(0);
#pragma unroll
      for (int kk = 0; kk < 16; ++kk) {
        a0 = __builtin_amdgcn_mfma_f32_16x16x32_bf16(af[kk], bfr[0][kk], a0, 0, 0, 0);
        a1 = __builtin_amdgcn_mfma_f32_16x16x32_bf16(af[kk], bfr[1][kk], a1, 0, 0, 0);
      }
    }
    // gates; low/high lane pairs compute identical h, low lanes write LDS
    {
      bool low = (col < 8);
#pragma unroll
      for (int r = 0; r < 4; ++r) {
        float g0 = a0[r] + xgv[0][r];
        float g1 = a1[r] + xgv[1][r];
        float p0 = __shfl_xor(g0, 8);
        float p1 = __shfl_xor(g1, 8);
        float iv = low ? g0 : p0;
        float fv = low ? p0 : g0;
        float gv = low ? g1 : p1;
        float ov = low ? p1 : g1;
        float cn = fsig(fv) * cst[r] + fsig(iv) * ftanh(gv);
        cst[r] = cn;
        float hv = fsig(ov) * ftanh(cn);
        if (low) tbuf[(quad * 4 + r) * 8 + (col & 7)] = f2bfu(hv);
      }
    }
    // wave-internal transpose readback (same wave: lgkmcnt suffices, no barrier)
    asm volatile("s_waitcnt lgkmcnt(0)" ::: "memory");
    if (l < 16) {
      short8 hrow = *(const short8*)(tbuf + l * 8);
      char* dst = (char*)hseq + (size_t)t * 65536 + g * 1024 + (wv * 16 + l) * 16;
      asm volatile("global_store_dwordx4 %0, %1, off sc0 sc1" :: "v"(dst), "v"(hrow) : "memory");
    }
    // no drain, no flag: the store IS the publish; it retires in background
  }
}

// ---------------- logits[t][b][k] = (hf|hb).w_out[k] + b_out, masked ----------------
__global__ __launch_bounds__(256) void logits_kernel(
    const unsigned short* __restrict__ hfp, const unsigned short* __restrict__ hbp,
    const unsigned short* __restrict__ wout, const float* __restrict__ bout,
    const int* __restrict__ y0, float* __restrict__ lg) {
  int t = blockIdx.x, tid = threadIdx.x;
  int b = tid >> 2, ks = tid & 3;
  int ytag = y0[(t + 1) * 64 + b];
  float mk = (ytag > 0) ? 1.f : 0.f;
  float av[6] = {0.f, 0.f, 0.f, 0.f, 0.f, 0.f};
  const char* pf = (const char*)hfp + (size_t)t * 65536;
  const char* pb = (const char*)hbp + (size_t)t * 65536;
  for (int uc = 0; uc < 64; ++uc) {
    short8 hv = *(const short8*)(pf + uc * 1024 + b * 16);
#pragma unroll
    for (int kk = 0; kk < 6; ++kk) {
      int k = ks * 6 + kk;
      short8 wv = *(const short8*)(wout + (size_t)k * 1024 + uc * 8);
#pragma unroll
      for (int j = 0; j < 8; ++j)
        av[kk] += bfu2f((unsigned short)hv[j]) * bfu2f((unsigned short)wv[j]);
    }
  }
  for (int uc = 0; uc < 64; ++uc) {
    short8 hv = *(const short8*)(pb + uc * 1024 + b * 16);
#pragma unroll
    for (int kk = 0; kk < 6; ++kk) {
      int k = ks * 6 + kk;
      short8 wv = *(const short8*)(wout + (size_t)k * 1024 + 512 + uc * 8);
#pragma unroll
      for (int j = 0; j < 8; ++j)
        av[kk] += bfu2f((unsigned short)hv[j]) * bfu2f((unsigned short)wv[j]);
    }
  }
#pragma unroll
  for (int kk = 0; kk < 6; ++kk) {
    int k = ks * 6 + kk;
    lg[((size_t)t * 64 + b) * 32 + k] = mk * (av[kk] + bout[k]);
  }
}

// ---------------- CRF forward + gold, one wave per batch ----------------
__global__ __launch_bounds__(64) void crf_kernel(
    const float* __restrict__ lg, const int* __restrict__ y0,
    const float* __restrict__ trans, float* __restrict__ res) {
  int b = blockIdx.x, l = threadIdx.x;
  __shared__ float tl[600];
  __shared__ float sc[24];
  for (int i = l; i < 576; i += 64) tl[(i / 24) * 25 + (i % 24)] = trans[i];
  if (l < 24) sc[l] = (l == 1) ? 0.f : NEGV;
  __syncthreads();
  float gold = 0.f;
  int lens = 0;
  for (int t = l; t < 256; t += 64) {
    int y1 = y0[(t + 1) * 64 + b];
    int yp = y0[t * 64 + b];
    if (y1 > 0) {
      gold += lg[((size_t)t * 64 + b) * 32 + y1] + tl[y1 * 25 + yp];
      lens += 1;
    }
  }
#pragma unroll
  for (int off = 32; off > 0; off >>= 1) {
    gold += __shfl_down(gold, off);
    lens += __shfl_down(lens, off);
  }
  gold = __shfl(gold, 0);
  lens = __shfl(lens, 0);
  int last = y0[lens * 64 + b];
  gold += tl[2 * 25 + last];
  int lc = (l < 24) ? l : 23;
  float trow[24];
#pragma unroll
  for (int j = 0; j < 24; ++j) trow[j] = tl[lc * 25 + j];
  for (int t = 0; t < 256; ++t) {
    int y1 = y0[(t + 1) * 64 + b];
    if (y1 > 0) {
      float ns = 0.f;
      if (l < 24) {
        float ht = lg[((size_t)t * 64 + b) * 32 + l];
        float mx = -3.0e38f;
        float sj[24];
#pragma unroll
        for (int j = 0; j < 24; ++j) {
          sj[j] = sc[j] + trow[j];
          mx = fmaxf(mx, sj[j]);
        }
        float sm = 0.f;
#pragma unroll
        for (int j = 0; j < 24; ++j) sm += __expf(sj[j] - mx);
        ns = ht + mx + __logf(sm);
      }
      __syncthreads();
      if (l < 24) sc[l] = ns;
      __syncthreads();
    }
  }
  float v = (l < 24) ? sc[l] + tl[2 * 25 + l] : -3.0e38f;
  float mx = v;
#pragma unroll
  for (int off = 32; off > 0; off >>= 1) mx = fmaxf(mx, __shfl_xor(mx, off));
  float se = (l < 24) ? __expf(v - mx) : 0.f;
#pragma unroll
  for (int off = 32; off > 0; off >>= 1) se += __shfl_xor(se, off);
  float Z = mx + __logf(se);
  if (l == 0) res[b] = Z - gold;
}

__global__ __launch_bounds__(64) void reduce_kernel(const float* __restrict__ res,
                                                    float* __restrict__ out) {
  int l = threadIdx.x;
  float v = res[l];
#pragma unroll
  for (int off = 32; off > 0; off >>= 1) v += __shfl_down(v, off);
  if (l == 0) out[0] = v * (1.0f / 64.0f);
}

extern "C" void kernel_launch(void* const* d_in, const int* in_sizes, int n_in,
                              void* d_out, int out_size, void* d_ws, size_t ws_size,
                              hipStream_t stream) {
  (void)in_sizes; (void)n_in; (void)out_size; (void)ws_size;
  const int* xw = (const int*)d_in[0];
  const int* y0 = (const int*)d_in[1];
  const float* emb = (const float*)d_in[2];
  const float* wihf = (const float*)d_in[3];
  const float* whhf = (const float*)d_in[4];
  const float* bfv = (const float*)d_in[5];
  const float* wihb = (const float*)d_in[6];
  const float* whhb = (const float*)d_in[7];
  const float* bbv = (const float*)d_in[8];
  const float* wo = (const float*)d_in[9];
  const float* bo = (const float*)d_in[10];
  const float* tr = (const float*)d_in[11];
  char* ws = (char*)d_ws;
  unsigned short* xg = (unsigned short*)(ws + 0);              // 134217728 B
  unsigned short* xbf = (unsigned short*)(ws + 134217728);     // 16777216 B
  unsigned short* wih_c = (unsigned short*)(ws + 150994944);   // 4194304 B
  unsigned short* whh_c = (unsigned short*)(ws + 155189248);   // 4194304 B
  unsigned short* wout_c = (unsigned short*)(ws + 159383552);  // 49152 B
  float* bias_c = (float*)(ws + 159432704);                    // 16384 B
  unsigned short* hfp = (unsigned short*)(ws + 159449088);     // 16777216 B
  unsigned short* hbp = (unsigned short*)(ws + 176226304);     // 16777216 B
  float* lg = (float*)(ws + 193003520);                        // 2097152 B
  float* res = (float*)(ws + 195104768);                       // 256 B

  // pre-poison h planes to the 0xFFFF sentinel (the data-is-flag protocol);
  // re-done every launch so graph replays are self-consistent.
  hipMemsetAsync(hfp, 0xFF, 16777216, stream);
  hipMemsetAsync(hbp, 0xFF, 16777216, stream);
  prep_kernel<<<16496, 256, 0, stream>>>(wihf, wihb, whhf, whhb, wo, bfv, bbv,
                                         wih_c, whh_c, wout_c, bias_c);
  gather_kernel<<<16384, 64, 0, stream>>>(xw, emb, xbf);
  gemm_xg_kernel<<<dim3(128, 32), 256, 0, stream>>>(xbf, wih_c, bias_c, xg);
  scan_kernel<<<512, 64, 0, stream>>>(whh_c, xg, hfp, hbp);
  logits_kernel<<<256, 256, 0, stream>>>(hfp, hbp, wout_c, bo, y0, lg);
  crf_kernel<<<64, 64, 0, stream>>>(lg, y0, tr, res);
  reduce_kernel<<<1, 64, 0, stream>>>(res, (float*)d_out);
}

// Round 6
// 1207.824 us; speedup vs baseline: 2.3657x; 1.0351x over previous
//
#include <hip/hip_runtime.h>

typedef __attribute__((ext_vector_type(8))) short short8;
typedef __attribute__((ext_vector_type(4))) float f32x4;

#define NEGV -10000.0f

__device__ __forceinline__ float bfu2f(unsigned short u) {
  unsigned int x = ((unsigned int)u) << 16;
  return __builtin_bit_cast(float, x);
}
__device__ __forceinline__ unsigned short f2bfu(float f) {
  unsigned int x = __builtin_bit_cast(unsigned int, f);
  x += 0x7fffu + ((x >> 16) & 1u);
  return (unsigned short)(x >> 16);
}
__device__ __forceinline__ float fsig(float x) {
  return 1.0f / (1.0f + __expf(-x));
}
__device__ __forceinline__ float ftanh(float x) {
  x = fminf(15.0f, fmaxf(-15.0f, x));
  float e = __expf(-2.0f * x);
  return (1.0f - e) / (1.0f + e);
}

// ---------------- prep: convert weights to bf16, build combined bias ----------------
__global__ __launch_bounds__(256) void prep_kernel(
    const float* __restrict__ wihf, const float* __restrict__ wihb,
    const float* __restrict__ whhf, const float* __restrict__ whhb,
    const float* __restrict__ wo, const float* __restrict__ bfv,
    const float* __restrict__ bbv,
    unsigned short* __restrict__ wih_c, unsigned short* __restrict__ whh_c,
    unsigned short* __restrict__ wout_c, float* __restrict__ bias_c) {
  size_t i = (size_t)blockIdx.x * 256 + threadIdx.x;
  const size_t n_half = 2048u * 512u;
  const size_t n_wih = 2u * n_half;
  const size_t n_wo = 24u * 1024u;
  if (i < n_wih) {
    float v = (i < n_half) ? wihf[i] : wihb[i - n_half];
    wih_c[i] = f2bfu(v);
  } else if (i < 2u * n_wih) {
    size_t j = i - n_wih;
    float v = (j < n_half) ? whhf[j] : whhb[j - n_half];
    whh_c[j] = f2bfu(v);
  } else if (i < 2u * n_wih + n_wo) {
    size_t j = i - 2u * n_wih;
    wout_c[j] = f2bfu(wo[j]);
  } else if (i < 2u * n_wih + n_wo + 4096u) {
    size_t j = i - 2u * n_wih - n_wo;
    bias_c[j] = (j < 2048u) ? bfv[j] : bbv[j - 2048u];
  }
}

// ---------------- gather: x_bf16[tb][e] = bf16(emb[xw[tb]][e]) ----------------
__global__ __launch_bounds__(64) void gather_kernel(
    const int* __restrict__ xw, const float* __restrict__ emb,
    unsigned short* __restrict__ xbf) {
  int tb = blockIdx.x;
  int l = threadIdx.x;
  int tok = xw[tb];
  const float* src = emb + (size_t)tok * 512 + l * 8;
  short8 o;
#pragma unroll
  for (int j = 0; j < 8; ++j) o[j] = (short)f2bfu(src[j]);
  *(short8*)(xbf + (size_t)tb * 512 + l * 8) = o;
}

// ---------------- GEMM: xg[16384][4096] = xbf[16384][512] @ wih_c[4096][512]^T + bias ----
__global__ __launch_bounds__(256) void gemm_xg_kernel(
    const unsigned short* __restrict__ A,   // [16384][512]
    const unsigned short* __restrict__ Bm,  // [4096][512]
    const float* __restrict__ bias,         // [4096]
    unsigned short* __restrict__ C) {       // [16384][4096] bf16
  __shared__ alignas(16) char As[16384];
  __shared__ alignas(16) char Bs[16384];
  int m0 = blockIdx.x * 128, n0 = blockIdx.y * 128;
  int tid = threadIdx.x;
  int wv = tid >> 6, l = tid & 63;
  int wm = wv >> 1, wn = wv & 1;
  int col = l & 15, quad = l >> 4;
  f32x4 zero4 = {0.f, 0.f, 0.f, 0.f};
  f32x4 acc[4][4];
#pragma unroll
  for (int i = 0; i < 4; ++i)
#pragma unroll
    for (int j = 0; j < 4; ++j) acc[i][j] = zero4;
  for (int kt = 0; kt < 8; ++kt) {
#pragma unroll
    for (int q = 0; q < 4; ++q) {
      int o = q * 4096 + tid * 16;
      int row = o >> 7;
      int cb = o & 127;
      int swz = cb ^ ((row & 7) << 4);
      short8 va = *(const short8*)(A + (size_t)(m0 + row) * 512 + kt * 64 + (cb >> 1));
      *(short8*)(As + row * 128 + swz) = va;
      short8 vb = *(const short8*)(Bm + (size_t)(n0 + row) * 512 + kt * 64 + (cb >> 1));
      *(short8*)(Bs + row * 128 + swz) = vb;
    }
    __syncthreads();
#pragma unroll
    for (int kk = 0; kk < 2; ++kk) {
      short8 af[4], bf8[4];
#pragma unroll
      for (int mi = 0; mi < 4; ++mi) {
        int r = wm * 64 + mi * 16 + col;
        int cb = kk * 64 + quad * 16;
        af[mi] = *(const short8*)(As + r * 128 + (cb ^ ((r & 7) << 4)));
      }
#pragma unroll
      for (int ni = 0; ni < 4; ++ni) {
        int r = wn * 64 + ni * 16 + col;
        int cb = kk * 64 + quad * 16;
        bf8[ni] = *(const short8*)(Bs + r * 128 + (cb ^ ((r & 7) << 4)));
      }
#pragma unroll
      for (int mi = 0; mi < 4; ++mi)
#pragma unroll
        for (int ni = 0; ni < 4; ++ni)
          acc[mi][ni] = __builtin_amdgcn_mfma_f32_16x16x32_bf16(af[mi], bf8[ni], acc[mi][ni], 0, 0, 0);
    }
    __syncthreads();
  }
#pragma unroll
  for (int ni = 0; ni < 4; ++ni) {
    int cg = n0 + wn * 64 + ni * 16 + col;
    float bv = bias[cg];
#pragma unroll
    for (int mi = 0; mi < 4; ++mi) {
#pragma unroll
      for (int r = 0; r < 4; ++r) {
        int rg = m0 + wm * 64 + mi * 16 + quad * 4 + r;
        C[(size_t)rg * 4096 + cg] = f2bfu(acc[mi][ni][r] + bv);
      }
    }
  }
}

// ---------------- persistent LSTM scan: wave-decoupled, XCD-local fast path ----------------
// 512 wgs x 64 threads. Cohort id c = wid%8 (dir=c&1, wv=c>>1), g = wid>>3:
// under round-robin dispatch all 64 waves of a cohort share one XCD/L2.
// Producers dual-store each 16B chunk: sc0 sc1 (IF$, guaranteed-visible) then
// sc0 (local L2, dirty-fresh). Readers poll sc0 first (L2 hit if co-located;
// a producer's sc0 store UPDATES any cached poison line, so retry is safe);
// after 8 failed rounds -> sticky fallback to sc0 sc1 polling (guaranteed
// progress under ANY dispatch mapping). h planes pre-poisoned 0xFFFF (bf16 NaN,
// unreachable since |h|<1); planes write-once per launch.
__global__ __launch_bounds__(64, 1) void scan_kernel(
    const unsigned short* __restrict__ whh,  // [2][2048][512] bf16
    const unsigned short* __restrict__ xg,   // [16384][4096] bf16
    unsigned short* __restrict__ hfp,
    unsigned short* __restrict__ hbp) {
  __shared__ alignas(16) unsigned short tbuf[128];  // 256B transpose scratch
  int wid = blockIdx.x;
  int l = threadIdx.x;
  int c = wid & 7;
  int dir = c & 1;
  int wv = (c >> 1) & 3;
  int g = wid >> 3;
  int u0 = g * 8;
  int col = l & 15, quad = l >> 4;
  int b_row = wv * 16 + quad * 4;
  // asm-resident w_hh fragments: 2 gate-pairs x 16 K-chunks
  short8 bfr[2][16];
#pragma unroll
  for (int n = 0; n < 2; ++n) {
    int blk = n * 2 + (col >> 3);  // 0..3 = i,f,g,o
    int gr = blk * 512 + u0 + (col & 7);
    const char* base = (const char*)(whh + ((size_t)dir * 2048 + gr) * 512 + quad * 8);
#pragma unroll
    for (int kk = 0; kk < 16; ++kk)
      asm volatile("global_load_dwordx4 %0, %1, off" : "=v"(bfr[n][kk]) : "v"(base + kk * 64));
  }
  unsigned short* hseq = dir ? hbp : hfp;
  int gc0 = dir * 2048 + (col >> 3) * 512 + u0 + (col & 7);  // n=0 gate col
  float cst[4] = {0.f, 0.f, 0.f, 0.f};
  f32x4 zero4 = {0.f, 0.f, 0.f, 0.f};
  short8 af[16];
  int usefast = 1;
  // xg ping-pong prefetch registers (statically named; rule-20 safe)
  unsigned int xA[8], xB[8];
  {  // prologue: xg for s=0
    int t0 = dir ? 255 : 0;
#pragma unroll
    for (int r = 0; r < 4; ++r) {
      const char* xa = (const char*)(xg + ((size_t)t0 * 64 + b_row + r) * 4096 + gc0);
      asm volatile("global_load_ushort %0, %1, off" : "=v"(xA[r]) : "v"(xa));
      asm volatile("global_load_ushort %0, %1, off" : "=v"(xA[4 + r]) : "v"(xa + 2048));
    }
  }
  asm volatile("s_waitcnt vmcnt(0)" ::: "memory");
  __builtin_amdgcn_sched_barrier(0);

#define SCAN_STEP(S_, XU_, XP_)                                                             \
  {                                                                                         \
    int s_ = (S_);                                                                          \
    int t_ = dir ? (255 - s_) : s_;                                                         \
    f32x4 a0 = zero4, a1 = zero4;                                                           \
    if (s_ > 0) {                                                                           \
      int tprev = t_ + (dir ? 1 : -1);                                                      \
      const char* pbase = (const char*)hseq + (size_t)tprev * 65536 + quad * 1024 +         \
                          (wv * 16 + col) * 16;                                             \
      unsigned long long bal = 1ull;                                                        \
      if (usefast) {                                                                        \
        for (int tryi = 0; tryi < 8 && bal != 0ull; ++tryi) {                               \
          _Pragma("unroll") for (int kk = 0; kk < 16; ++kk)                                 \
              asm volatile("global_load_dwordx4 %0, %1, off sc0"                            \
                           : "=v"(af[kk]) : "v"(pbase + kk * 4096));                        \
          asm volatile("s_waitcnt vmcnt(0)" ::: "memory");                                  \
          __builtin_amdgcn_sched_barrier(0);                                                \
          unsigned int st_ = 0u;                                                            \
          _Pragma("unroll") for (int kk = 0; kk < 16; ++kk)                                 \
              st_ |= (((unsigned short)af[kk][0]) == 0xFFFFu) ? 1u : 0u;                    \
          bal = __ballot(st_ != 0u);                                                        \
        }                                                                                   \
        if (bal != 0ull) usefast = 0;                                                       \
      }                                                                                     \
      while (bal != 0ull) {                                                                 \
        _Pragma("unroll") for (int kk = 0; kk < 16; ++kk)                                   \
            asm volatile("global_load_dwordx4 %0, %1, off sc0 sc1"                          \
                         : "=v"(af[kk]) : "v"(pbase + kk * 4096));                          \
        asm volatile("s_waitcnt vmcnt(0)" ::: "memory");                                    \
        __builtin_amdgcn_sched_barrier(0);                                                  \
        unsigned int st_ = 0u;                                                              \
        _Pragma("unroll") for (int kk = 0; kk < 16; ++kk)                                   \
            st_ |= (((unsigned short)af[kk][0]) == 0xFFFFu) ? 1u : 0u;                      \
        bal = __ballot(st_ != 0u);                                                          \
      }                                                                                     \
      __builtin_amdgcn_s_setprio(1);                                                        \
      __builtin_amdgcn_sched_barrier(0);                                                    \
      _Pragma("unroll") for (int kk = 0; kk < 16; ++kk) {                                   \
        a0 = __builtin_amdgcn_mfma_f32_16x16x32_bf16(af[kk], bfr[0][kk], a0, 0, 0, 0);      \
        a1 = __builtin_amdgcn_mfma_f32_16x16x32_bf16(af[kk], bfr[1][kk], a1, 0, 0, 0);      \
      }                                                                                     \
    }                                                                                       \
    {                                                                                       \
      int sn = (s_ < 255) ? (s_ + 1) : 255;                                                 \
      int tn = dir ? (255 - sn) : sn;                                                       \
      _Pragma("unroll") for (int r = 0; r < 4; ++r) {                                       \
        const char* xa = (const char*)(xg + ((size_t)tn * 64 + b_row + r) * 4096 + gc0);    \
        asm volatile("global_load_ushort %0, %1, off" : "=v"(XP_[r]) : "v"(xa));            \
        asm volatile("global_load_ushort %0, %1, off" : "=v"(XP_[4 + r]) : "v"(xa + 2048)); \
      }                                                                                     \
    }                                                                                       \
    {                                                                                       \
      bool low = (col < 8);                                                                 \
      _Pragma("unroll") for (int r = 0; r < 4; ++r) {                                       \
        float g0 = a0[r] + bfu2f((unsigned short)XU_[r]);                                   \
        float g1 = a1[r] + bfu2f((unsigned short)XU_[4 + r]);                               \
        float p0 = __shfl_xor(g0, 8);                                                       \
        float p1 = __shfl_xor(g1, 8);                                                       \
        float iv = low ? g0 : p0;                                                           \
        float fv = low ? p0 : g0;                                                           \
        float gv = low ? g1 : p1;                                                           \
        float ov = low ? p1 : g1;                                                           \
        float cn = fsig(fv) * cst[r] + fsig(iv) * ftanh(gv);                                \
        cst[r] = cn;                                                                        \
        float hv = fsig(ov) * ftanh(cn);                                                    \
        if (low) tbuf[(quad * 4 + r) * 8 + (col & 7)] = f2bfu(hv);                          \
      }                                                                                     \
    }                                                                                       \
    asm volatile("s_waitcnt lgkmcnt(0)" ::: "memory");                                      \
    if (l < 16) {                                                                           \
      short8 hrow = *(const short8*)(tbuf + l * 8);                                         \
      char* dst = (char*)hseq + (size_t)t_ * 65536 + g * 1024 + (wv * 16 + l) * 16;         \
      asm volatile("global_store_dwordx4 %0, %1, off sc0 sc1" ::"v"(dst), "v"(hrow)         \
                   : "memory");                                                             \
      asm volatile("global_store_dwordx4 %0, %1, off sc0" ::"v"(dst), "v"(hrow)             \
                   : "memory");                                                             \
    }                                                                                       \
    __builtin_amdgcn_s_setprio(0);                                                          \
  }

  for (int it = 0; it < 128; ++it) {
    SCAN_STEP(2 * it, xA, xB);
    SCAN_STEP(2 * it + 1, xB, xA);
  }
#undef SCAN_STEP
}

// ---------------- logits[t][b][k] = (hf|hb).w_out[k] + b_out, masked ----------------
__global__ __launch_bounds__(256) void logits_kernel(
    const unsigned short* __restrict__ hfp, const unsigned short* __restrict__ hbp,
    const unsigned short* __restrict__ wout, const float* __restrict__ bout,
    const int* __restrict__ y0, float* __restrict__ lg) {
  int t = blockIdx.x, tid = threadIdx.x;
  int b = tid >> 2, ks = tid & 3;
  int ytag = y0[(t + 1) * 64 + b];
  float mk = (ytag > 0) ? 1.f : 0.f;
  float av[6] = {0.f, 0.f, 0.f, 0.f, 0.f, 0.f};
  const char* pf = (const char*)hfp + (size_t)t * 65536;
  const char* pb = (const char*)hbp + (size_t)t * 65536;
  for (int uc = 0; uc < 64; ++uc) {
    short8 hv = *(const short8*)(pf + uc * 1024 + b * 16);
#pragma unroll
    for (int kk = 0; kk < 6; ++kk) {
      int k = ks * 6 + kk;
      short8 wv = *(const short8*)(wout + (size_t)k * 1024 + uc * 8);
#pragma unroll
      for (int j = 0; j < 8; ++j)
        av[kk] += bfu2f((unsigned short)hv[j]) * bfu2f((unsigned short)wv[j]);
    }
  }
  for (int uc = 0; uc < 64; ++uc) {
    short8 hv = *(const short8*)(pb + uc * 1024 + b * 16);
#pragma unroll
    for (int kk = 0; kk < 6; ++kk) {
      int k = ks * 6 + kk;
      short8 wv = *(const short8*)(wout + (size_t)k * 1024 + 512 + uc * 8);
#pragma unroll
      for (int j = 0; j < 8; ++j)
        av[kk] += bfu2f((unsigned short)hv[j]) * bfu2f((unsigned short)wv[j]);
    }
  }
#pragma unroll
  for (int kk = 0; kk < 6; ++kk) {
    int k = ks * 6 + kk;
    lg[((size_t)t * 64 + b) * 32 + k] = mk * (av[kk] + bout[k]);
  }
}

// ---------------- CRF forward + gold, one wave per batch ----------------
__global__ __launch_bounds__(64) void crf_kernel(
    const float* __restrict__ lg, const int* __restrict__ y0,
    const float* __restrict__ trans, float* __restrict__ res) {
  int b = blockIdx.x, l = threadIdx.x;
  __shared__ float tl[600];
  __shared__ float sc[24];
  for (int i = l; i < 576; i += 64) tl[(i / 24) * 25 + (i % 24)] = trans[i];
  if (l < 24) sc[l] = (l == 1) ? 0.f : NEGV;
  __syncthreads();
  float gold = 0.f;
  int lens = 0;
  for (int t = l; t < 256; t += 64) {
    int y1 = y0[(t + 1) * 64 + b];
    int yp = y0[t * 64 + b];
    if (y1 > 0) {
      gold += lg[((size_t)t * 64 + b) * 32 + y1] + tl[y1 * 25 + yp];
      lens += 1;
    }
  }
#pragma unroll
  for (int off = 32; off > 0; off >>= 1) {
    gold += __shfl_down(gold, off);
    lens += __shfl_down(lens, off);
  }
  gold = __shfl(gold, 0);
  lens = __shfl(lens, 0);
  int last = y0[lens * 64 + b];
  gold += tl[2 * 25 + last];
  int lc = (l < 24) ? l : 23;
  float trow[24];
#pragma unroll
  for (int j = 0; j < 24; ++j) trow[j] = tl[lc * 25 + j];
  for (int t = 0; t < 256; ++t) {
    int y1 = y0[(t + 1) * 64 + b];
    if (y1 > 0) {
      float ns = 0.f;
      if (l < 24) {
        float ht = lg[((size_t)t * 64 + b) * 32 + l];
        float mx = -3.0e38f;
        float sj[24];
#pragma unroll
        for (int j = 0; j < 24; ++j) {
          sj[j] = sc[j] + trow[j];
          mx = fmaxf(mx, sj[j]);
        }
        float sm = 0.f;
#pragma unroll
        for (int j = 0; j < 24; ++j) sm += __expf(sj[j] - mx);
        ns = ht + mx + __logf(sm);
      }
      __syncthreads();
      if (l < 24) sc[l] = ns;
      __syncthreads();
    }
  }
  float v = (l < 24) ? sc[l] + tl[2 * 25 + l] : -3.0e38f;
  float mx = v;
#pragma unroll
  for (int off = 32; off > 0; off >>= 1) mx = fmaxf(mx, __shfl_xor(mx, off));
  float se = (l < 24) ? __expf(v - mx) : 0.f;
#pragma unroll
  for (int off = 32; off > 0; off >>= 1) se += __shfl_xor(se, off);
  float Z = mx + __logf(se);
  if (l == 0) res[b] = Z - gold;
}

__global__ __launch_bounds__(64) void reduce_kernel(const float* __restrict__ res,
                                                    float* __restrict__ out) {
  int l = threadIdx.x;
  float v = res[l];
#pragma unroll
  for (int off = 32; off > 0; off >>= 1) v += __shfl_down(v, off);
  if (l == 0) out[0] = v * (1.0f / 64.0f);
}

extern "C" void kernel_launch(void* const* d_in, const int* in_sizes, int n_in,
                              void* d_out, int out_size, void* d_ws, size_t ws_size,
                              hipStream_t stream) {
  (void)in_sizes; (void)n_in; (void)out_size; (void)ws_size;
  const int* xw = (const int*)d_in[0];
  const int* y0 = (const int*)d_in[1];
  const float* emb = (const float*)d_in[2];
  const float* wihf = (const float*)d_in[3];
  const float* whhf = (const float*)d_in[4];
  const float* bfv = (const float*)d_in[5];
  const float* wihb = (const float*)d_in[6];
  const float* whhb = (const float*)d_in[7];
  const float* bbv = (const float*)d_in[8];
  const float* wo = (const float*)d_in[9];
  const float* bo = (const float*)d_in[10];
  const float* tr = (const float*)d_in[11];
  char* ws = (char*)d_ws;
  unsigned short* xg = (unsigned short*)(ws + 0);              // 134217728 B
  unsigned short* xbf = (unsigned short*)(ws + 134217728);     // 16777216 B
  unsigned short* wih_c = (unsigned short*)(ws + 150994944);   // 4194304 B
  unsigned short* whh_c = (unsigned short*)(ws + 155189248);   // 4194304 B
  unsigned short* wout_c = (unsigned short*)(ws + 159383552);  // 49152 B
  float* bias_c = (float*)(ws + 159432704);                    // 16384 B
  unsigned short* hfp = (unsigned short*)(ws + 159449088);     // 16777216 B
  unsigned short* hbp = (unsigned short*)(ws + 176226304);     // 16777216 B
  float* lg = (float*)(ws + 193003520);                        // 2097152 B
  float* res = (float*)(ws + 195104768);                       // 256 B

  // pre-poison h planes to the 0xFFFF sentinel (data-is-flag protocol);
  // re-done every launch so graph replays are self-consistent.
  hipMemsetAsync(hfp, 0xFF, 16777216, stream);
  hipMemsetAsync(hbp, 0xFF, 16777216, stream);
  prep_kernel<<<16496, 256, 0, stream>>>(wihf, wihb, whhf, whhb, wo, bfv, bbv,
                                         wih_c, whh_c, wout_c, bias_c);
  gather_kernel<<<16384, 64, 0, stream>>>(xw, emb, xbf);
  gemm_xg_kernel<<<dim3(128, 32), 256, 0, stream>>>(xbf, wih_c, bias_c, xg);
  scan_kernel<<<512, 64, 0, stream>>>(whh_c, xg, hfp, hbp);
  logits_kernel<<<256, 256, 0, stream>>>(hfp, hbp, wout_c, bo, y0, lg);
  crf_kernel<<<64, 64, 0, stream>>>(lg, y0, tr, res);
  reduce_kernel<<<1, 64, 0, stream>>>(res, (float*)d_out);
}